// Round 2
// baseline (3166.638 us; speedup 1.0000x reference)
//
#include <hip/hip_runtime.h>

// BiLSTM-CRF on MI355X (all float32 inputs; f32->bf16 conversion for MFMA paths).
// K0 pack W_ih | K0b bias/wfc | Kz zero barrier | K1 features | K2 input-gate GEMM
// (bias fused, bf16 out) | K3 recurrent BiLSTM (16 persistent WGs, spin barrier) |
// K4 FC projection | K5 Viterbi.

#define DEV __device__ __forceinline__
typedef unsigned short u16;
typedef unsigned int   u32;
typedef unsigned char  u8;
using short8 = __attribute__((ext_vector_type(8))) short;
using f32x4  = __attribute__((ext_vector_type(4))) float;

DEV float bf2f(u16 u){ union{u32 i; float f;} v; v.i = ((u32)u)<<16; return v.f; }
DEV u16 f2bf(float f){ u32 x = __float_as_uint(f); return (u16)((x + 0x7fffu + ((x>>16)&1u)) >> 16); }
DEV float sigf(float x){ return __builtin_amdgcn_rcpf(1.f + __expf(-x)); }
DEV float tanh_f(float x){ return 1.f - 2.f*__builtin_amdgcn_rcpf(__expf(2.f*x) + 1.f); }

typedef __attribute__((address_space(1))) const u32 GU;
typedef __attribute__((address_space(3))) u32 LU;
DEV void gld_lds16(const void* g, void* l){
  __builtin_amdgcn_global_load_lds((GU*)g, (LU*)l, 16, 0, 0);
}

// ---------------- ws layout (aliased; total ~162MB) ----------------
// gi (bf16, 128MB) dead after K3 -> P/DL/PSI alias it.
// feat (27.3MB) dead after K2 -> hcat (32MB) aliases it.
static const size_t OFF_GI   = 0;
static const size_t OFF_P    = 0;
static const size_t OFF_DL   = OFF_P  + (size_t)32768*16*4;   // 2MB
static const size_t OFF_PSI  = OFF_DL + (size_t)32768*16*4;   // 2MB (+0.5MB)
static const size_t OFF_B    = (size_t)134217728;             // feat then hcat
static const size_t OFF_WIH  = OFF_B    + (size_t)33554432;
static const size_t OFF_HST  = OFF_WIH  + (size_t)1703936;
static const size_t OFF_BIAS = OFF_HST  + 131072;
static const size_t OFF_WFC  = OFF_BIAS + 8192;
static const size_t OFF_BAR  = OFF_WFC  + 256;
static const size_t REQUIRED = OFF_BAR  + 256;

// ---------------- Kz: zero the barrier counters ----------------
__global__ void kz_zero(u32* p){ p[threadIdx.x] = 0u; }

// ---------------- K0: pack W_ih (f32 -> bf16 [2048][416]) ----------------
__global__ void k0_pack(const float* __restrict__ wihf, const float* __restrict__ wihb,
                        u16* __restrict__ wih)
{
  int n = blockIdx.x, tid = threadIdx.x;
  const float* src = (n < 1024) ? (wihf + (size_t)n*400) : (wihb + (size_t)(n-1024)*400);
  u32* dst = (u32*)(wih + (size_t)n*416);
  if (tid < 208){
    int j = tid*2;
    u32 v = 0u;
    if (j < 400){
      float2 f = *(const float2*)(src + j);
      v = (u32)f2bf(f.x) | ((u32)f2bf(f.y) << 16);
    }
    dst[tid] = v;
  }
}

// ---------------- K0b: bias sums (fp32) + wfc = fc_w @ wd ----------------
__global__ void k0_misc(const float* bihf, const float* bhhf, const float* bihb, const float* bhhb,
                        const float* fcw, const float* wdp, float* bias, float* wfc)
{
  int tid = threadIdx.x;
  for (int n = tid; n < 2048; n += 256){
    bias[n] = (n < 1024) ? (bihf[n] + bhhf[n]) : (bihb[n-1024] + bhhb[n-1024]);
  }
  if (tid < 16){
    float s = 0.f;
    for (int k = 0; k < 512; k++) s += fcw[tid*512 + k] * wdp[k];
    wfc[tid] = s;
  }
}

// ---------------- K1: features -> feat[s*64+b][416] bf16 ----------------
__global__ __launch_bounds__(256) void k1_feat(
    const int* __restrict__ X, const int* __restrict__ tg, const int* __restrict__ ch,
    const float* __restrict__ etab, const float* __restrict__ ttab, const float* __restrict__ ctab,
    const float* __restrict__ cw, const float* __restrict__ cb, u16* __restrict__ feat)
{
  const int sb = blockIdx.x, b = blockIdx.y, tid = threadIdx.x;
  __shared__ float ce_s[66*60];
  __shared__ float w_s[150*52];
  // embed rows: 4 rows x 150 word-pairs
  for (int i = tid; i < 600; i += 256){
    int wl = i/150, j = i - wl*150;
    int s = sb*4 + wl;
    int idx = X[b*512 + s];
    float2 f = *(const float2*)(etab + (size_t)idx*300 + j*2);
    *(u32*)(feat + (size_t)(s*64 + b)*416 + j*2) = (u32)f2bf(f.x) | ((u32)f2bf(f.y) << 16);
  }
  // tag rows: 4 x 25 pairs
  for (int i = tid; i < 100; i += 256){
    int wl = i/25, j = i - wl*25;
    int s = sb*4 + wl;
    int idx = tg[b*512 + s];
    float2 f = *(const float2*)(ttab + (size_t)idx*50 + j*2);
    *(u32*)(feat + (size_t)(s*64 + b)*416 + 300 + j*2) = (u32)f2bf(f.x) | ((u32)f2bf(f.y) << 16);
  }
  // zero pad cols 400..415
  if (tid < 32){
    int wl = tid>>3, j = tid&7;
    int s = sb*4 + wl;
    *(u32*)(feat + (size_t)(s*64 + b)*416 + 400 + j*2) = 0u;
  }
  // char embeddings, 66 halo rows x 50
  for (int i = tid; i < 3300; i += 256){
    int qq = i/50, ce = i - qq*50;
    int p = sb*64 - 1 + qq;
    float v = 0.f;
    if (p >= 0 && p < 8192){
      int ci = ch[b*8192 + p];
      v = ctab[ci*50 + ce];
    }
    ce_s[qq*60 + ce] = v;
  }
  // conv weights: w_s[(cc*3+dc)*52 + ce]
  for (int i = tid; i < 7500; i += 256){
    int cc = i/150, r2 = i - cc*150;
    int ce = r2/3, dc = r2 - ce*3;
    w_s[(cc*3 + dc)*52 + ce] = cw[i];
  }
  __syncthreads();
  const int li = tid & 15, jg = tid >> 4;
  float acc[4][3];
  #pragma unroll
  for (int k=0;k<4;k++){ acc[k][0]=0.f; acc[k][1]=0.f; acc[k][2]=0.f; }
  #pragma unroll
  for (int dc = 0; dc < 3; dc++){
    for (int ceb = 0; ceb < 48; ceb += 4){
      f32x4 w0 = *(const f32x4*)&w_s[((3*jg+0)*3 + dc)*52 + ceb];
      f32x4 w1 = *(const f32x4*)&w_s[((3*jg+1)*3 + dc)*52 + ceb];
      f32x4 w2 = *(const f32x4*)&w_s[((3*jg+2)*3 + dc)*52 + ceb];
      #pragma unroll
      for (int k = 0; k < 4; k++){
        f32x4 cv = *(const f32x4*)&ce_s[(16*k + li + dc)*60 + ceb];
        #pragma unroll
        for (int e = 0; e < 4; e++){
          acc[k][0] += cv[e]*w0[e];
          acc[k][1] += cv[e]*w1[e];
          acc[k][2] += cv[e]*w2[e];
        }
      }
    }
    float w0a = w_s[((3*jg+0)*3+dc)*52 + 48], w0b = w_s[((3*jg+0)*3+dc)*52 + 49];
    float w1a = w_s[((3*jg+1)*3+dc)*52 + 48], w1b = w_s[((3*jg+1)*3+dc)*52 + 49];
    float w2a = w_s[((3*jg+2)*3+dc)*52 + 48], w2b = w_s[((3*jg+2)*3+dc)*52 + 49];
    #pragma unroll
    for (int k = 0; k < 4; k++){
      float ca = ce_s[(16*k + li + dc)*60 + 48];
      float cb2 = ce_s[(16*k + li + dc)*60 + 49];
      acc[k][0] += ca*w0a + cb2*w0b;
      acc[k][1] += ca*w1a + cb2*w1b;
      acc[k][2] += ca*w2a + cb2*w2b;
    }
  }
  #pragma unroll
  for (int m = 1; m < 16; m <<= 1)
    #pragma unroll
    for (int k=0;k<4;k++)
      #pragma unroll
      for (int c=0;c<3;c++)
        acc[k][c] = fmaxf(acc[k][c], __shfl_xor(acc[k][c], m, 64));
  if (li == 0){
    #pragma unroll
    for (int k=0;k<4;k++)
      #pragma unroll
      for (int c=0;c<3;c++){
        int cc = 3*jg + c;
        int s = sb*4 + k;
        feat[(size_t)(s*64 + b)*416 + 350 + cc] = f2bf(acc[k][c] + cb[cc]);
      }
  }
  if (tid < 128){
    int pl = tid & 63, cc = 48 + (tid >> 6);
    float a2 = 0.f;
    #pragma unroll
    for (int dc = 0; dc < 3; dc++){
      for (int ceb = 0; ceb < 48; ceb += 4){
        f32x4 wv = *(const f32x4*)&w_s[(cc*3 + dc)*52 + ceb];
        f32x4 cv = *(const f32x4*)&ce_s[(pl + dc)*60 + ceb];
        a2 += cv[0]*wv[0] + cv[1]*wv[1] + cv[2]*wv[2] + cv[3]*wv[3];
      }
      a2 += ce_s[(pl+dc)*60 + 48]*w_s[(cc*3+dc)*52 + 48]
          + ce_s[(pl+dc)*60 + 49]*w_s[(cc*3+dc)*52 + 49];
    }
    #pragma unroll
    for (int m = 1; m < 16; m <<= 1) a2 = fmaxf(a2, __shfl_xor(a2, m, 64));
    if ((tid & 15) == 0){
      int s = sb*4 + ((tid & 63) >> 4);
      feat[(size_t)(s*64 + b)*416 + 350 + cc] = f2bf(a2 + cb[cc]);
    }
  }
}

// ---------------- K2: gi = bf16(feat @ wih^T + bias)  [32768 x 2048] ----------------
__global__ __launch_bounds__(256) void k2_gemm(
    const u16* __restrict__ featp, const u16* __restrict__ wihp,
    const float* __restrict__ bias, u16* __restrict__ gi)
{
  const int m0 = blockIdx.x*128, n0 = blockIdx.y*128;
  const int tid = threadIdx.x, wv = tid>>6, lane = tid&63;
  const int lr = lane & 15, lq = lane >> 4;
  const int wm = (wv>>1)*64, wn = (wv&1)*64;
  __shared__ u16 As[4096], Bs[4096];
  f32x4 acc[4][4];
  #pragma unroll
  for (int a=0;a<4;a++)
    #pragma unroll
    for (int c=0;c<4;c++) acc[a][c] = (f32x4){0.f,0.f,0.f,0.f};
  for (int k0 = 0; k0 < 416; k0 += 32){
    __syncthreads();
    #pragma unroll
    for (int i = 0; i < 2; i++){
      int c = i*4 + wv;
      gld_lds16(featp + (size_t)(m0 + c*16 + (lane>>2))*416 + k0 + (lane&3)*8, &As[c*512]);
      gld_lds16(wihp  + (size_t)(n0 + c*16 + (lane>>2))*416 + k0 + (lane&3)*8, &Bs[c*512]);
    }
    __syncthreads();
    short8 af[4], bfr[4];
    #pragma unroll
    for (int mt=0; mt<4; mt++) af[mt]  = *(const short8*)(As + (wm + mt*16 + lr)*32 + lq*8);
    #pragma unroll
    for (int nt=0; nt<4; nt++) bfr[nt] = *(const short8*)(Bs + (wn + nt*16 + lr)*32 + lq*8);
    #pragma unroll
    for (int mt=0; mt<4; mt++)
      #pragma unroll
      for (int nt=0; nt<4; nt++)
        acc[mt][nt] = __builtin_amdgcn_mfma_f32_16x16x32_bf16(af[mt], bfr[nt], acc[mt][nt], 0,0,0);
  }
  #pragma unroll
  for (int nt=0; nt<4; nt++){
    float bv = bias[n0 + wn + nt*16 + lr];
    #pragma unroll
    for (int mt=0; mt<4; mt++)
      #pragma unroll
      for (int r=0; r<4; r++)
        gi[(size_t)(m0 + wm + mt*16 + lq*4 + r)*2048 + n0 + wn + nt*16 + lr]
            = f2bf(acc[mt][nt][r] + bv);
  }
}

// ---------------- K3: recurrent BiLSTM ----------------
// 16 WGs x 256 thr. dir = blk>>3, hidden slice j0 = (blk&7)*32 -> 128 gate rows.
// W_hh (f32 -> bf16) persistent in VGPRs; H ping-pong in global (swizzled bf16);
// per-direction spin barrier (monotonic device-scope counter).
__global__ __launch_bounds__(256, 1) void k3_lstm(
    const float* __restrict__ whhf, const float* __restrict__ whhb,
    const u16* __restrict__ gin,
    u16* __restrict__ hcat, u16* __restrict__ hstate, u32* __restrict__ bar)
{
  const int dir = blockIdx.x >> 3;
  const int j0  = (blockIdx.x & 7) * 32;
  const int tid = threadIdx.x;
  const int wv = tid >> 6, lane = tid & 63;
  const int lr = lane & 15, lq = lane >> 4;
  const float* whh = dir ? whhb : whhf;
  u16* hstd = hstate + (size_t)dir*32768;
  u32* cnt = bar + dir*16;

  __shared__ u16 Hs[16384];        // 32KB staged H (swizzled image)
  __shared__ float gsm[4*64*34];   // gate exchange [g][b][34]

  // persistent B fragments (wave wv == gate g): 2 n-tiles x 8 k-steps, f32->bf16
  short8 bf[2][8];
  #pragma unroll
  for (int nt = 0; nt < 2; nt++)
    #pragma unroll
    for (int kk = 0; kk < 8; kk++){
      const float* wr = whh + (size_t)(wv*256 + j0 + nt*16 + lr)*256 + kk*32 + lq*8;
      f32x4 w0 = *(const f32x4*)wr;
      f32x4 w1 = *(const f32x4*)(wr + 4);
      short8 sv;
      #pragma unroll
      for (int e = 0; e < 4; e++){ sv[e] = (short)f2bf(w0[e]); sv[4+e] = (short)f2bf(w1[e]); }
      bf[nt][kk] = sv;
    }

  const int jj0 = (tid & 15)*2, bb = (tid >> 4)*4;
  float cst[4][2];
  #pragma unroll
  for (int u = 0; u < 4; u++){ cst[u][0] = 0.f; cst[u][1] = 0.f; }

  #pragma unroll 1
  for (int t = 0; t < 512; t++){
    const int s = dir ? (511 - t) : t;
    // prefetch input-gate contributions (bf16 pairs, bias already fused)
    u32 gv[4][4];
    #pragma unroll
    for (int u = 0; u < 4; u++)
      #pragma unroll
      for (int g = 0; g < 4; g++)
        gv[u][g] = *(const u32*)(gin + (size_t)(s*64 + bb + u)*2048 + dir*1024 + g*256 + j0 + jj0);

    if (t > 0){
      __syncthreads();
      if (tid == 0){
        __builtin_amdgcn_fence(__ATOMIC_RELEASE, "agent");
        __hip_atomic_fetch_add(cnt, 1u, __ATOMIC_RELEASE, __HIP_MEMORY_SCOPE_AGENT);
        const u32 target = 8u*(u32)t;
        while (__hip_atomic_load(cnt, __ATOMIC_RELAXED, __HIP_MEMORY_SCOPE_AGENT) < target)
          __builtin_amdgcn_s_sleep(8);
        __builtin_amdgcn_fence(__ATOMIC_ACQUIRE, "agent");
      }
      __syncthreads();
      // stage H_{t-1} (32KB linear copy; global image already swizzled)
      const u16* src = hstd + ((t-1)&1)*16384;
      #pragma unroll
      for (int i = 0; i < 8; i++){
        int c = i*4 + wv;
        gld_lds16(src + c*512 + lane*8, &Hs[c*512]);
      }
      __syncthreads();
      f32x4 acc[2][4];
      #pragma unroll
      for (int nt=0; nt<2; nt++)
        #pragma unroll
        for (int mt=0; mt<4; mt++) acc[nt][mt] = (f32x4){0.f,0.f,0.f,0.f};
      #pragma unroll
      for (int kk = 0; kk < 8; kk++){
        short8 af[4];
        #pragma unroll
        for (int mt = 0; mt < 4; mt++){
          int boff = (((16*mt + lr)*512 + (kk*32 + lq*8)*2)) ^ ((lr & 7) << 4);
          af[mt] = *(const short8*)((const char*)Hs + boff);
        }
        #pragma unroll
        for (int nt = 0; nt < 2; nt++)
          #pragma unroll
          for (int mt = 0; mt < 4; mt++)
            acc[nt][mt] = __builtin_amdgcn_mfma_f32_16x16x32_bf16(af[mt], bf[nt][kk], acc[nt][mt], 0,0,0);
      }
      #pragma unroll
      for (int nt = 0; nt < 2; nt++)
        #pragma unroll
        for (int mt = 0; mt < 4; mt++)
          #pragma unroll
          for (int r = 0; r < 4; r++)
            gsm[wv*2176 + (16*mt + 4*lq + r)*34 + nt*16 + lr] = acc[nt][mt][r];
      __syncthreads();
    }
    // cell update: thread owns (b=bb+u, jj=jj0+p)
    u16* hstw = hstd + (t&1)*16384;
    #pragma unroll
    for (int u = 0; u < 4; u++){
      const int b = bb + u;
      u16 hb16[2];
      #pragma unroll
      for (int p = 0; p < 2; p++){
        float g4[4];
        #pragma unroll
        for (int g = 0; g < 4; g++){
          u32 v = gv[u][g];
          float base = bf2f((u16)(p ? (v >> 16) : (v & 0xffffu)));
          float m = (t > 0) ? gsm[g*2176 + b*34 + jj0 + p] : 0.f;
          g4[g] = base + m;
        }
        float iv = sigf(g4[0]), fv = sigf(g4[1]);
        float ggv = tanh_f(g4[2]), ov = sigf(g4[3]);
        float c = fv*cst[u][p] + iv*ggv;
        cst[u][p] = c;
        hb16[p] = f2bf(ov * tanh_f(c));
      }
      u32 pack = (u32)hb16[0] | ((u32)hb16[1] << 16);
      *(u32*)(hcat + (size_t)(s*64 + b)*512 + dir*256 + j0 + jj0) = pack;
      const int jb = j0 + jj0;
      const u32 boff = (u32)((b*512 + (jb>>3)*16) ^ ((b&7)<<4)) + (jb&7)*2;
      *(u32*)((char*)hstw + boff) = pack;
    }
  }
}

// ---------------- K4: P = Hcat @ fc_w^T + fc_b + lm*wfc  [32768 x 16] fp32 ----------------
__global__ __launch_bounds__(256) void k4_fc(
    const u16* __restrict__ hcat, const float* __restrict__ fcw, const float* __restrict__ fcb,
    const float* __restrict__ lmp, const float* __restrict__ wfc, float* __restrict__ Pout)
{
  const int wv = threadIdx.x >> 6, lane = threadIdx.x & 63;
  const int lr = lane & 15, lq = lane >> 4;
  const int mt = blockIdx.x*4 + wv;
  short8 bfr[16];
  #pragma unroll
  for (int kk = 0; kk < 16; kk++){
    const float* wr = fcw + (size_t)lr*512 + kk*32 + lq*8;
    f32x4 w0 = *(const f32x4*)wr;
    f32x4 w1 = *(const f32x4*)(wr + 4);
    short8 sv;
    #pragma unroll
    for (int e = 0; e < 4; e++){ sv[e] = (short)f2bf(w0[e]); sv[4+e] = (short)f2bf(w1[e]); }
    bfr[kk] = sv;
  }
  f32x4 acc = (f32x4){0.f,0.f,0.f,0.f};
  #pragma unroll
  for (int kk = 0; kk < 16; kk++){
    short8 af = *(const short8*)(hcat + (size_t)(mt*16 + lr)*512 + kk*32 + lq*8);
    acc = __builtin_amdgcn_mfma_f32_16x16x32_bf16(af, bfr[kk], acc, 0,0,0);
  }
  const int cur = lr;
  float fb = fcb[cur];
  float wf = wfc[cur];
  #pragma unroll
  for (int r = 0; r < 4; r++){
    int m = mt*16 + lq*4 + r;
    int b = m & 63, s = m >> 6;
    float lmv = lmp[b*512 + s];
    Pout[(size_t)m*16 + cur] = acc[r] + fb + lmv*wf;
  }
}

// ---------------- K5: Viterbi (one wave per batch element) ----------------
__global__ __launch_bounds__(64) void k5_vit(
    const float* __restrict__ Pg, const float* __restrict__ Am,
    float* __restrict__ dout, float* __restrict__ dl, u8* __restrict__ psi)
{
  const int b = blockIdx.x, lane = threadIdx.x;
  const int cur = lane >> 2, q = lane & 3;
  float Ar[4];
  #pragma unroll
  for (int r = 0; r < 4; r++) Ar[r] = Am[(4*q + r)*16 + cur];
  float val = Pg[(size_t)b*16 + cur];
  if (q == 0) dl[(size_t)b*16 + cur] = val;
  for (int s = 1; s < 512; s++){
    float x = Pg[(size_t)(s*64 + b)*16 + cur];
    float best = -3.0e38f; int bi = 0;
    #pragma unroll
    for (int r = 0; r < 4; r++){
      float dp = __shfl(val, (4*q + r)*4, 64);
      float sc = (dp + Ar[r]) + x;
      if (sc > best){ best = sc; bi = 4*q + r; }
    }
    #pragma unroll
    for (int m = 1; m <= 2; m <<= 1){
      float ov = __shfl_xor(best, m, 64);
      int   oi = __shfl_xor(bi, m, 64);
      if (ov > best || (ov == best && oi < bi)){ best = ov; bi = oi; }
    }
    val = best;
    if (q == 0){
      dl[(size_t)(s*64 + b)*16 + cur] = best;
      psi[(size_t)(s*64 + b)*16 + cur] = (u8)bi;
    }
  }
  __syncthreads();
  float bv = val; int bix = cur;
  #pragma unroll
  for (int m = 1; m < 64; m <<= 1){
    float ov = __shfl_xor(bv, m, 64);
    int   oi = __shfl_xor(bix, m, 64);
    if (ov > bv || (ov == bv && oi < bix)){ bv = ov; bix = oi; }
  }
  int tag = bix;
  float score = bv;
  if (lane == 0) dout[b*512 + 511] = (float)tag;
  int pvn = 0; float dvn = 0.f;
  if (lane < 16){
    pvn = psi[(size_t)(511*64 + b)*16 + lane];
    dvn = dl[(size_t)(510*64 + b)*16 + lane];
  }
  for (int t = 510; t >= 0; t--){
    int pv = pvn; float dv = dvn;
    if (t > 0 && lane < 16){
      pvn = psi[(size_t)(t*64 + b)*16 + lane];
      dvn = dl[(size_t)((t-1)*64 + b)*16 + lane];
    }
    int prev = __shfl(pv, tag, 64);
    score += __shfl(dv, prev, 64);
    if (lane == 0) dout[b*512 + t] = (float)prev;
    tag = prev;
  }
  if (lane == 0) dout[32768 + b] = score;
}

// ---------------- launcher ----------------
extern "C" void kernel_launch(void* const* d_in, const int* in_sizes, int n_in,
                              void* d_out, int out_size, void* d_ws, size_t ws_size,
                              hipStream_t stream)
{
  (void)in_sizes; (void)n_in; (void)out_size;
  if (ws_size < REQUIRED) return;   // diagnostic guard: clean fail if ws too small

  const int*   X    = (const int*)d_in[0];
  const float* lm   = (const float*)d_in[1];
  const int*   tg   = (const int*)d_in[2];
  const int*   ch   = (const int*)d_in[3];
  const float* etab = (const float*)d_in[4];
  const float* ttab = (const float*)d_in[5];
  const float* ctab = (const float*)d_in[6];
  const float* cw   = (const float*)d_in[7];
  const float* cb   = (const float*)d_in[8];
  const float* wihf = (const float*)d_in[9];
  const float* whhf = (const float*)d_in[10];
  const float* bihf = (const float*)d_in[11];
  const float* bhhf = (const float*)d_in[12];
  const float* wihb = (const float*)d_in[13];
  const float* whhb = (const float*)d_in[14];
  const float* bihb = (const float*)d_in[15];
  const float* bhhb = (const float*)d_in[16];
  const float* fcw  = (const float*)d_in[17];
  const float* fcb  = (const float*)d_in[18];
  const float* Am   = (const float*)d_in[19];
  const float* wdp  = (const float*)d_in[20];

  char* ws = (char*)d_ws;
  u16*   gi   = (u16*)(ws + OFF_GI);
  u16*   feat = (u16*)(ws + OFF_B);
  u16*   hcat = (u16*)(ws + OFF_B);
  u16*   wih  = (u16*)(ws + OFF_WIH);
  u16*   hst  = (u16*)(ws + OFF_HST);
  float* Pg   = (float*)(ws + OFF_P);
  float* dlt  = (float*)(ws + OFF_DL);
  u8*    psi  = (u8*)(ws + OFF_PSI);
  float* bias = (float*)(ws + OFF_BIAS);
  float* wfc  = (float*)(ws + OFF_WFC);
  u32*   bar  = (u32*)(ws + OFF_BAR);
  float* dout = (float*)d_out;

  kz_zero<<<1, 64, 0, stream>>>(bar);
  k0_pack<<<2048, 256, 0, stream>>>(wihf, wihb, wih);
  k0_misc<<<1, 256, 0, stream>>>(bihf, bhhf, bihb, bhhb, fcw, wdp, bias, wfc);
  k1_feat<<<dim3(128, 64), 256, 0, stream>>>(X, tg, ch, etab, ttab, ctab, cw, cb, feat);
  k2_gemm<<<dim3(256, 16), 256, 0, stream>>>(feat, wih, bias, gi);
  k3_lstm<<<16, 256, 0, stream>>>(whhf, whhb, gi, hcat, hst, bar);
  k4_fc<<<512, 256, 0, stream>>>(hcat, fcw, fcb, lm, wfc, Pg);
  k5_vit<<<64, 64, 0, stream>>>(Pg, Am, dout, dlt, psi);
}

// Round 3
// 2875.388 us; speedup vs baseline: 1.1013x; 1.1013x over previous
//
#include <hip/hip_runtime.h>

// BiLSTM-CRF on MI355X (all float32 inputs; f32->bf16 conversion for MFMA paths).
// K0 pack W_ih | K0b bias/wfc | Kz zero barrier | K1 features | K2 input-gate GEMM
// (bias fused, bf16 out) | K3 recurrent BiLSTM (16 persistent WGs, fence-free
// sc0sc1 exchange + relaxed spin barrier) | K4 FC projection | K5 Viterbi (prefetched).

#define DEV __device__ __forceinline__
typedef unsigned short u16;
typedef unsigned int   u32;
typedef unsigned char  u8;
using short8 = __attribute__((ext_vector_type(8))) short;
using f32x4  = __attribute__((ext_vector_type(4))) float;

DEV float bf2f(u16 u){ union{u32 i; float f;} v; v.i = ((u32)u)<<16; return v.f; }
DEV u16 f2bf(float f){ u32 x = __float_as_uint(f); return (u16)((x + 0x7fffu + ((x>>16)&1u)) >> 16); }
DEV float sigf(float x){ return __builtin_amdgcn_rcpf(1.f + __expf(-x)); }
DEV float tanh_f(float x){ return 1.f - 2.f*__builtin_amdgcn_rcpf(__expf(2.f*x) + 1.f); }

typedef __attribute__((address_space(1))) const u32 GU;
typedef __attribute__((address_space(3))) u32 LU;
DEV void gld_lds16(const void* g, void* l){
  __builtin_amdgcn_global_load_lds((GU*)g, (LU*)l, 16, 0, 0);
}
// coherent variant: SC0|SC1 (bypass L1/L2, read device coherence point)
DEV void gld_lds16_cc(const void* g, void* l){
  __builtin_amdgcn_global_load_lds((GU*)g, (LU*)l, 16, 0, 0x11);
}
// device-coherent store/load (bypass L1/L2)
DEV void st_cc_u32(void* p, u32 v){
  asm volatile("global_store_dword %0, %1, off sc0 sc1" :: "v"(p), "v"(v) : "memory");
}
DEV u32 ld_cc_u32(const u32* p){
  u32 v;
  asm volatile("global_load_dword %0, %1, off sc0 sc1\n\ts_waitcnt vmcnt(0)"
               : "=v"(v) : "v"(p) : "memory");
  return v;
}

// ---------------- ws layout (aliased; total ~162MB) ----------------
static const size_t OFF_GI   = 0;
static const size_t OFF_P    = 0;
static const size_t OFF_DL   = OFF_P  + (size_t)32768*16*4;
static const size_t OFF_PSI  = OFF_DL + (size_t)32768*16*4;
static const size_t OFF_B    = (size_t)134217728;             // feat then hcat
static const size_t OFF_WIH  = OFF_B    + (size_t)33554432;
static const size_t OFF_HST  = OFF_WIH  + (size_t)1703936;
static const size_t OFF_BIAS = OFF_HST  + 131072;
static const size_t OFF_WFC  = OFF_BIAS + 8192;
static const size_t OFF_BAR  = OFF_WFC  + 256;
static const size_t REQUIRED = OFF_BAR  + 256;

__global__ void kz_zero(u32* p){ p[threadIdx.x] = 0u; }

// ---------------- K0: pack W_ih (f32 -> bf16 [2048][416]) ----------------
__global__ void k0_pack(const float* __restrict__ wihf, const float* __restrict__ wihb,
                        u16* __restrict__ wih)
{
  int n = blockIdx.x, tid = threadIdx.x;
  const float* src = (n < 1024) ? (wihf + (size_t)n*400) : (wihb + (size_t)(n-1024)*400);
  u32* dst = (u32*)(wih + (size_t)n*416);
  if (tid < 208){
    int j = tid*2;
    u32 v = 0u;
    if (j < 400){
      float2 f = *(const float2*)(src + j);
      v = (u32)f2bf(f.x) | ((u32)f2bf(f.y) << 16);
    }
    dst[tid] = v;
  }
}

// ---------------- K0b: bias sums (fp32) + wfc = fc_w @ wd ----------------
__global__ void k0_misc(const float* bihf, const float* bhhf, const float* bihb, const float* bhhb,
                        const float* fcw, const float* wdp, float* bias, float* wfc)
{
  int tid = threadIdx.x;
  for (int n = tid; n < 2048; n += 256){
    bias[n] = (n < 1024) ? (bihf[n] + bhhf[n]) : (bihb[n-1024] + bhhb[n-1024]);
  }
  if (tid < 16){
    float s = 0.f;
    for (int k = 0; k < 512; k++) s += fcw[tid*512 + k] * wdp[k];
    wfc[tid] = s;
  }
}

// ---------------- K1: features -> feat[s*64+b][416] bf16 ----------------
__global__ __launch_bounds__(256) void k1_feat(
    const int* __restrict__ X, const int* __restrict__ tg, const int* __restrict__ ch,
    const float* __restrict__ etab, const float* __restrict__ ttab, const float* __restrict__ ctab,
    const float* __restrict__ cw, const float* __restrict__ cb, u16* __restrict__ feat)
{
  const int sb = blockIdx.x, b = blockIdx.y, tid = threadIdx.x;
  __shared__ float ce_s[66*60];
  __shared__ float w_s[150*52];
  for (int i = tid; i < 600; i += 256){
    int wl = i/150, j = i - wl*150;
    int s = sb*4 + wl;
    int idx = X[b*512 + s];
    float2 f = *(const float2*)(etab + (size_t)idx*300 + j*2);
    *(u32*)(feat + (size_t)(s*64 + b)*416 + j*2) = (u32)f2bf(f.x) | ((u32)f2bf(f.y) << 16);
  }
  for (int i = tid; i < 100; i += 256){
    int wl = i/25, j = i - wl*25;
    int s = sb*4 + wl;
    int idx = tg[b*512 + s];
    float2 f = *(const float2*)(ttab + (size_t)idx*50 + j*2);
    *(u32*)(feat + (size_t)(s*64 + b)*416 + 300 + j*2) = (u32)f2bf(f.x) | ((u32)f2bf(f.y) << 16);
  }
  if (tid < 32){
    int wl = tid>>3, j = tid&7;
    int s = sb*4 + wl;
    *(u32*)(feat + (size_t)(s*64 + b)*416 + 400 + j*2) = 0u;
  }
  for (int i = tid; i < 3300; i += 256){
    int qq = i/50, ce = i - qq*50;
    int p = sb*64 - 1 + qq;
    float v = 0.f;
    if (p >= 0 && p < 8192){
      int ci = ch[b*8192 + p];
      v = ctab[ci*50 + ce];
    }
    ce_s[qq*60 + ce] = v;
  }
  for (int i = tid; i < 7500; i += 256){
    int cc = i/150, r2 = i - cc*150;
    int ce = r2/3, dc = r2 - ce*3;
    w_s[(cc*3 + dc)*52 + ce] = cw[i];
  }
  __syncthreads();
  const int li = tid & 15, jg = tid >> 4;
  float acc[4][3];
  #pragma unroll
  for (int k=0;k<4;k++){ acc[k][0]=0.f; acc[k][1]=0.f; acc[k][2]=0.f; }
  #pragma unroll
  for (int dc = 0; dc < 3; dc++){
    for (int ceb = 0; ceb < 48; ceb += 4){
      f32x4 w0 = *(const f32x4*)&w_s[((3*jg+0)*3 + dc)*52 + ceb];
      f32x4 w1 = *(const f32x4*)&w_s[((3*jg+1)*3 + dc)*52 + ceb];
      f32x4 w2 = *(const f32x4*)&w_s[((3*jg+2)*3 + dc)*52 + ceb];
      #pragma unroll
      for (int k = 0; k < 4; k++){
        f32x4 cv = *(const f32x4*)&ce_s[(16*k + li + dc)*60 + ceb];
        #pragma unroll
        for (int e = 0; e < 4; e++){
          acc[k][0] += cv[e]*w0[e];
          acc[k][1] += cv[e]*w1[e];
          acc[k][2] += cv[e]*w2[e];
        }
      }
    }
    float w0a = w_s[((3*jg+0)*3+dc)*52 + 48], w0b = w_s[((3*jg+0)*3+dc)*52 + 49];
    float w1a = w_s[((3*jg+1)*3+dc)*52 + 48], w1b = w_s[((3*jg+1)*3+dc)*52 + 49];
    float w2a = w_s[((3*jg+2)*3+dc)*52 + 48], w2b = w_s[((3*jg+2)*3+dc)*52 + 49];
    #pragma unroll
    for (int k = 0; k < 4; k++){
      float ca = ce_s[(16*k + li + dc)*60 + 48];
      float cb2 = ce_s[(16*k + li + dc)*60 + 49];
      acc[k][0] += ca*w0a + cb2*w0b;
      acc[k][1] += ca*w1a + cb2*w1b;
      acc[k][2] += ca*w2a + cb2*w2b;
    }
  }
  #pragma unroll
  for (int m = 1; m < 16; m <<= 1)
    #pragma unroll
    for (int k=0;k<4;k++)
      #pragma unroll
      for (int c=0;c<3;c++)
        acc[k][c] = fmaxf(acc[k][c], __shfl_xor(acc[k][c], m, 64));
  if (li == 0){
    #pragma unroll
    for (int k=0;k<4;k++)
      #pragma unroll
      for (int c=0;c<3;c++){
        int cc = 3*jg + c;
        int s = sb*4 + k;
        feat[(size_t)(s*64 + b)*416 + 350 + cc] = f2bf(acc[k][c] + cb[cc]);
      }
  }
  if (tid < 128){
    int pl = tid & 63, cc = 48 + (tid >> 6);
    float a2 = 0.f;
    #pragma unroll
    for (int dc = 0; dc < 3; dc++){
      for (int ceb = 0; ceb < 48; ceb += 4){
        f32x4 wv = *(const f32x4*)&w_s[(cc*3 + dc)*52 + ceb];
        f32x4 cv = *(const f32x4*)&ce_s[(pl + dc)*60 + ceb];
        a2 += cv[0]*wv[0] + cv[1]*wv[1] + cv[2]*wv[2] + cv[3]*wv[3];
      }
      a2 += ce_s[(pl+dc)*60 + 48]*w_s[(cc*3+dc)*52 + 48]
          + ce_s[(pl+dc)*60 + 49]*w_s[(cc*3+dc)*52 + 49];
    }
    #pragma unroll
    for (int m = 1; m < 16; m <<= 1) a2 = fmaxf(a2, __shfl_xor(a2, m, 64));
    if ((tid & 15) == 0){
      int s = sb*4 + ((tid & 63) >> 4);
      feat[(size_t)(s*64 + b)*416 + 350 + cc] = f2bf(a2 + cb[cc]);
    }
  }
}

// ---------------- K2: gi = bf16(feat @ wih^T + bias)  [32768 x 2048] ----------------
__global__ __launch_bounds__(256) void k2_gemm(
    const u16* __restrict__ featp, const u16* __restrict__ wihp,
    const float* __restrict__ bias, u16* __restrict__ gi)
{
  const int m0 = blockIdx.x*128, n0 = blockIdx.y*128;
  const int tid = threadIdx.x, wv = tid>>6, lane = tid&63;
  const int lr = lane & 15, lq = lane >> 4;
  const int wm = (wv>>1)*64, wn = (wv&1)*64;
  __shared__ u16 As[4096], Bs[4096];
  f32x4 acc[4][4];
  #pragma unroll
  for (int a=0;a<4;a++)
    #pragma unroll
    for (int c=0;c<4;c++) acc[a][c] = (f32x4){0.f,0.f,0.f,0.f};
  for (int k0 = 0; k0 < 416; k0 += 32){
    __syncthreads();
    #pragma unroll
    for (int i = 0; i < 2; i++){
      int c = i*4 + wv;
      gld_lds16(featp + (size_t)(m0 + c*16 + (lane>>2))*416 + k0 + (lane&3)*8, &As[c*512]);
      gld_lds16(wihp  + (size_t)(n0 + c*16 + (lane>>2))*416 + k0 + (lane&3)*8, &Bs[c*512]);
    }
    __syncthreads();
    short8 af[4], bfr[4];
    #pragma unroll
    for (int mt=0; mt<4; mt++) af[mt]  = *(const short8*)(As + (wm + mt*16 + lr)*32 + lq*8);
    #pragma unroll
    for (int nt=0; nt<4; nt++) bfr[nt] = *(const short8*)(Bs + (wn + nt*16 + lr)*32 + lq*8);
    #pragma unroll
    for (int mt=0; mt<4; mt++)
      #pragma unroll
      for (int nt=0; nt<4; nt++)
        acc[mt][nt] = __builtin_amdgcn_mfma_f32_16x16x32_bf16(af[mt], bfr[nt], acc[mt][nt], 0,0,0);
  }
  #pragma unroll
  for (int nt=0; nt<4; nt++){
    float bv = bias[n0 + wn + nt*16 + lr];
    #pragma unroll
    for (int mt=0; mt<4; mt++)
      #pragma unroll
      for (int r=0; r<4; r++)
        gi[(size_t)(m0 + wm + mt*16 + lq*4 + r)*2048 + n0 + wn + nt*16 + lr]
            = f2bf(acc[mt][nt][r] + bv);
  }
}

// ---------------- K3: recurrent BiLSTM (fence-free coherent exchange) ----------------
__global__ __launch_bounds__(256, 1) void k3_lstm(
    const float* __restrict__ whhf, const float* __restrict__ whhb,
    const u16* __restrict__ gin,
    u16* __restrict__ hcat, u16* __restrict__ hstate, u32* __restrict__ bar)
{
  const int dir = blockIdx.x >> 3;
  const int j0  = (blockIdx.x & 7) * 32;
  const int tid = threadIdx.x;
  const int wv = tid >> 6, lane = tid & 63;
  const int lr = lane & 15, lq = lane >> 4;
  const float* whh = dir ? whhb : whhf;
  u16* hstd = hstate + (size_t)dir*32768;
  u32* cnt = bar + dir*16;

  __shared__ u16 Hs[16384];        // 32KB staged H (swizzled image)
  __shared__ float gsm[4*64*34];   // gate exchange [g][b][34]

  // persistent B fragments (wave wv == gate g): 2 n-tiles x 8 k-steps, f32->bf16
  short8 bf[2][8];
  #pragma unroll
  for (int nt = 0; nt < 2; nt++)
    #pragma unroll
    for (int kk = 0; kk < 8; kk++){
      const float* wr = whh + (size_t)(wv*256 + j0 + nt*16 + lr)*256 + kk*32 + lq*8;
      f32x4 w0 = *(const f32x4*)wr;
      f32x4 w1 = *(const f32x4*)(wr + 4);
      short8 sv;
      #pragma unroll
      for (int e = 0; e < 4; e++){ sv[e] = (short)f2bf(w0[e]); sv[4+e] = (short)f2bf(w1[e]); }
      bf[nt][kk] = sv;
    }

  const int jj0 = (tid & 15)*2, bb = (tid >> 4)*4;
  float cst[4][2];
  #pragma unroll
  for (int u = 0; u < 4; u++){ cst[u][0] = 0.f; cst[u][1] = 0.f; }

  u32 gv[4][4];

  #pragma unroll 1
  for (int t = 0; t < 512; t++){
    const int s = dir ? (511 - t) : t;

    if (t == 0){
      #pragma unroll
      for (int u = 0; u < 4; u++)
        #pragma unroll
        for (int g = 0; g < 4; g++)
          gv[u][g] = *(const u32*)(gin + (size_t)(s*64 + bb + u)*2048 + dir*1024 + g*256 + j0 + jj0);
    } else {
      // drain h stores (sc0sc1 -> coherence point), then signal + poll (no fences)
      asm volatile("s_waitcnt vmcnt(0)" ::: "memory");
      __syncthreads();
      if (tid == 0)
        __hip_atomic_fetch_add(cnt, 1u, __ATOMIC_RELAXED, __HIP_MEMORY_SCOPE_AGENT);
      // overlap next-gate loads with the barrier wait
      #pragma unroll
      for (int u = 0; u < 4; u++)
        #pragma unroll
        for (int g = 0; g < 4; g++)
          gv[u][g] = *(const u32*)(gin + (size_t)(s*64 + bb + u)*2048 + dir*1024 + g*256 + j0 + jj0);
      const u32 target = 8u*(u32)t;
      while (ld_cc_u32(cnt) < target) __builtin_amdgcn_s_sleep(1);
      // stage H_{t-1} (32KB; global image already swizzled), coherent reads
      const u16* src = hstd + ((t-1)&1)*16384;
      #pragma unroll
      for (int i = 0; i < 8; i++){
        int c = i*4 + wv;
        gld_lds16_cc(src + c*512 + lane*8, &Hs[c*512]);
      }
      __syncthreads();
      f32x4 acc[2][4];
      #pragma unroll
      for (int nt=0; nt<2; nt++)
        #pragma unroll
        for (int mt=0; mt<4; mt++) acc[nt][mt] = (f32x4){0.f,0.f,0.f,0.f};
      #pragma unroll
      for (int kk = 0; kk < 8; kk++){
        short8 af[4];
        #pragma unroll
        for (int mt = 0; mt < 4; mt++){
          int boff = (((16*mt + lr)*512 + (kk*32 + lq*8)*2)) ^ ((lr & 7) << 4);
          af[mt] = *(const short8*)((const char*)Hs + boff);
        }
        #pragma unroll
        for (int nt = 0; nt < 2; nt++)
          #pragma unroll
          for (int mt = 0; mt < 4; mt++)
            acc[nt][mt] = __builtin_amdgcn_mfma_f32_16x16x32_bf16(af[mt], bf[nt][kk], acc[nt][mt], 0,0,0);
      }
      #pragma unroll
      for (int nt = 0; nt < 2; nt++)
        #pragma unroll
        for (int mt = 0; mt < 4; mt++)
          #pragma unroll
          for (int r = 0; r < 4; r++)
            gsm[wv*2176 + (16*mt + 4*lq + r)*34 + nt*16 + lr] = acc[nt][mt][r];
      __syncthreads();
    }
    // cell update: thread owns (b=bb+u, jj=jj0+p)
    u16* hstw = hstd + (t&1)*16384;
    #pragma unroll
    for (int u = 0; u < 4; u++){
      const int b = bb + u;
      u16 hb16[2];
      #pragma unroll
      for (int p = 0; p < 2; p++){
        float g4[4];
        #pragma unroll
        for (int g = 0; g < 4; g++){
          u32 v = gv[u][g];
          float base = bf2f((u16)(p ? (v >> 16) : (v & 0xffffu)));
          float m = (t > 0) ? gsm[g*2176 + b*34 + jj0 + p] : 0.f;
          g4[g] = base + m;
        }
        float iv = sigf(g4[0]), fv = sigf(g4[1]);
        float ggv = tanh_f(g4[2]), ov = sigf(g4[3]);
        float c = fv*cst[u][p] + iv*ggv;
        cst[u][p] = c;
        hb16[p] = f2bf(ov * tanh_f(c));
      }
      u32 pack = (u32)hb16[0] | ((u32)hb16[1] << 16);
      *(u32*)(hcat + (size_t)(s*64 + b)*512 + dir*256 + j0 + jj0) = pack;
      const int jb = j0 + jj0;
      const u32 boff = (u32)((b*512 + (jb>>3)*16) ^ ((b&7)<<4)) + (jb&7)*2;
      st_cc_u32((char*)hstw + boff, pack);
    }
  }
}

// ---------------- K4: P = Hcat @ fc_w^T + fc_b + lm*wfc  [32768 x 16] fp32 ----------------
__global__ __launch_bounds__(256) void k4_fc(
    const u16* __restrict__ hcat, const float* __restrict__ fcw, const float* __restrict__ fcb,
    const float* __restrict__ lmp, const float* __restrict__ wfc, float* __restrict__ Pout)
{
  const int wv = threadIdx.x >> 6, lane = threadIdx.x & 63;
  const int lr = lane & 15, lq = lane >> 4;
  const int mt = blockIdx.x*4 + wv;
  short8 bfr[16];
  #pragma unroll
  for (int kk = 0; kk < 16; kk++){
    const float* wr = fcw + (size_t)lr*512 + kk*32 + lq*8;
    f32x4 w0 = *(const f32x4*)wr;
    f32x4 w1 = *(const f32x4*)(wr + 4);
    short8 sv;
    #pragma unroll
    for (int e = 0; e < 4; e++){ sv[e] = (short)f2bf(w0[e]); sv[4+e] = (short)f2bf(w1[e]); }
    bfr[kk] = sv;
  }
  f32x4 acc = (f32x4){0.f,0.f,0.f,0.f};
  #pragma unroll
  for (int kk = 0; kk < 16; kk++){
    short8 af = *(const short8*)(hcat + (size_t)(mt*16 + lr)*512 + kk*32 + lq*8);
    acc = __builtin_amdgcn_mfma_f32_16x16x32_bf16(af, bfr[kk], acc, 0,0,0);
  }
  const int cur = lr;
  float fb = fcb[cur];
  float wf = wfc[cur];
  #pragma unroll
  for (int r = 0; r < 4; r++){
    int m = mt*16 + lq*4 + r;
    int b = m & 63, s = m >> 6;
    float lmv = lmp[b*512 + s];
    Pout[(size_t)m*16 + cur] = acc[r] + fb + lmv*wf;
  }
}

// ---------------- K5: Viterbi (one wave per batch element, prefetched) ----------------
__global__ __launch_bounds__(64) void k5_vit(
    const float* __restrict__ Pg, const float* __restrict__ Am,
    float* __restrict__ dout, float* __restrict__ dl, u8* __restrict__ psi)
{
  const int b = blockIdx.x, lane = threadIdx.x;
  const int cur = lane >> 2, q = lane & 3;
  float Ar[4];
  #pragma unroll
  for (int r = 0; r < 4; r++) Ar[r] = Am[(4*q + r)*16 + cur];
  float val = Pg[(size_t)b*16 + cur];
  if (q == 0) dl[(size_t)b*16 + cur] = val;
  // forward scan with 4-deep x prefetch
  float xr[4];
  #pragma unroll
  for (int i = 0; i < 4; i++) xr[i] = Pg[(size_t)((1+i)*64 + b)*16 + cur];
  for (int s = 1; s < 512; s++){
    float x = xr[(s-1)&3];
    if (s + 4 < 512) xr[(s-1)&3] = Pg[(size_t)((s+4)*64 + b)*16 + cur];
    float best = -3.0e38f; int bi = 0;
    #pragma unroll
    for (int r = 0; r < 4; r++){
      float dp = __shfl(val, (4*q + r)*4, 64);
      float sc = (dp + Ar[r]) + x;
      if (sc > best){ best = sc; bi = 4*q + r; }
    }
    #pragma unroll
    for (int m = 1; m <= 2; m <<= 1){
      float ov = __shfl_xor(best, m, 64);
      int   oi = __shfl_xor(bi, m, 64);
      if (ov > best || (ov == best && oi < bi)){ best = ov; bi = oi; }
    }
    val = best;
    if (q == 0){
      dl[(size_t)(s*64 + b)*16 + cur] = best;
      psi[(size_t)(s*64 + b)*16 + cur] = (u8)bi;
    }
  }
  __syncthreads();
  float bv = val; int bix = cur;
  #pragma unroll
  for (int m = 1; m < 64; m <<= 1){
    float ov = __shfl_xor(bv, m, 64);
    int   oi = __shfl_xor(bix, m, 64);
    if (ov > bv || (ov == bv && oi < bix)){ bv = ov; bix = oi; }
  }
  int tag = bix;
  float score = bv;
  if (lane == 0) dout[b*512 + 511] = (float)tag;
  // backtrace with 4-deep ring prefetch: iteration t uses psi[t+1], dl[t]
  int pvr[4]; float dvr[4];
  #pragma unroll
  for (int i = 0; i < 4; i++){
    if (lane < 16){
      pvr[i] = psi[(size_t)((511-i)*64 + b)*16 + lane];
      dvr[i] = dl[(size_t)((510-i)*64 + b)*16 + lane];
    }
  }
  for (int t = 510; t >= 0; t--){
    const int slot = (510 - t) & 3;
    int pv = pvr[slot]; float dv = dvr[slot];
    if (t >= 4 && lane < 16){
      pvr[slot] = psi[(size_t)((t-3)*64 + b)*16 + lane];
      dvr[slot] = dl[(size_t)((t-4)*64 + b)*16 + lane];
    }
    int prev = __shfl(pv, tag, 64);
    score += __shfl(dv, prev, 64);
    if (lane == 0) dout[b*512 + t] = (float)prev;
    tag = prev;
  }
  if (lane == 0) dout[32768 + b] = score;
}

// ---------------- launcher ----------------
extern "C" void kernel_launch(void* const* d_in, const int* in_sizes, int n_in,
                              void* d_out, int out_size, void* d_ws, size_t ws_size,
                              hipStream_t stream)
{
  (void)in_sizes; (void)n_in; (void)out_size;
  if (ws_size < REQUIRED) return;

  const int*   X    = (const int*)d_in[0];
  const float* lm   = (const float*)d_in[1];
  const int*   tg   = (const int*)d_in[2];
  const int*   ch   = (const int*)d_in[3];
  const float* etab = (const float*)d_in[4];
  const float* ttab = (const float*)d_in[5];
  const float* ctab = (const float*)d_in[6];
  const float* cw   = (const float*)d_in[7];
  const float* cb   = (const float*)d_in[8];
  const float* wihf = (const float*)d_in[9];
  const float* whhf = (const float*)d_in[10];
  const float* bihf = (const float*)d_in[11];
  const float* bhhf = (const float*)d_in[12];
  const float* wihb = (const float*)d_in[13];
  const float* whhb = (const float*)d_in[14];
  const float* bihb = (const float*)d_in[15];
  const float* bhhb = (const float*)d_in[16];
  const float* fcw  = (const float*)d_in[17];
  const float* fcb  = (const float*)d_in[18];
  const float* Am   = (const float*)d_in[19];
  const float* wdp  = (const float*)d_in[20];

  char* ws = (char*)d_ws;
  u16*   gi   = (u16*)(ws + OFF_GI);
  u16*   feat = (u16*)(ws + OFF_B);
  u16*   hcat = (u16*)(ws + OFF_B);
  u16*   wih  = (u16*)(ws + OFF_WIH);
  u16*   hst  = (u16*)(ws + OFF_HST);
  float* Pg   = (float*)(ws + OFF_P);
  float* dlt  = (float*)(ws + OFF_DL);
  u8*    psi  = (u8*)(ws + OFF_PSI);
  float* bias = (float*)(ws + OFF_BIAS);
  float* wfc  = (float*)(ws + OFF_WFC);
  u32*   bar  = (u32*)(ws + OFF_BAR);
  float* dout = (float*)d_out;

  kz_zero<<<1, 64, 0, stream>>>(bar);
  k0_pack<<<2048, 256, 0, stream>>>(wihf, wihb, wih);
  k0_misc<<<1, 256, 0, stream>>>(bihf, bhhf, bihb, bhhb, fcw, wdp, bias, wfc);
  k1_feat<<<dim3(128, 64), 256, 0, stream>>>(X, tg, ch, etab, ttab, ctab, cw, cb, feat);
  k2_gemm<<<dim3(256, 16), 256, 0, stream>>>(feat, wih, bias, gi);
  k3_lstm<<<16, 256, 0, stream>>>(whhf, whhb, gi, hcat, hst, bar);
  k4_fc<<<512, 256, 0, stream>>>(hcat, fcw, fcb, lm, wfc, Pg);
  k5_vit<<<64, 64, 0, stream>>>(Pg, Am, dout, dlt, psi);
}

// Round 4
// 1798.248 us; speedup vs baseline: 1.7610x; 1.5990x over previous
//
#include <hip/hip_runtime.h>

// BiLSTM-CRF on MI355X. Round 3 rewrite: K3 uses BATCH-SPLIT (no inter-block
// sync at all) with int8-quantized W_hh + h, full direction per CU.
// K0 pack W_ih | K0q quantize W_hh->i8 frags | K0b bias/wfc | K1 features |
// K2 input-gate GEMM (bias fused, bf16, scattered to per-block layout) |
// K3 recurrent BiLSTM (8 blocks x 1024 thr, i8 MFMA, LDS-only exchange) |
// K4 FC projection | K5 Viterbi (prefetched).

#define DEV __device__ __forceinline__
typedef unsigned short u16;
typedef unsigned int   u32;
typedef unsigned char  u8;
typedef signed char    s8;
using short8  = __attribute__((ext_vector_type(8))) short;
using ushort8 = __attribute__((ext_vector_type(8))) unsigned short;
using f32x4   = __attribute__((ext_vector_type(4))) float;
using int4v   = __attribute__((ext_vector_type(4))) int;

DEV float bf2f(u16 u){ union{u32 i; float f;} v; v.i = ((u32)u)<<16; return v.f; }
DEV u16 f2bf(float f){ u32 x = __float_as_uint(f); return (u16)((x + 0x7fffu + ((x>>16)&1u)) >> 16); }
DEV float sigf(float x){ return __builtin_amdgcn_rcpf(1.f + __expf(-x)); }
DEV float tanh_f(float x){ return 1.f - 2.f*__builtin_amdgcn_rcpf(__expf(2.f*x) + 1.f); }

typedef __attribute__((address_space(1))) const u32 GU;
typedef __attribute__((address_space(3))) u32 LU;
DEV void gld_lds16(const void* g, void* l){
  __builtin_amdgcn_global_load_lds((GU*)g, (LU*)l, 16, 0, 0);
}

// ---------------- ws layout (aliased; total ~170MB) ----------------
// gi (bf16, 128MB, block-swizzled) dead after K3 -> P/DL/PSI alias it.
// feat (27.3MB) dead after K2 -> hcat (33.5MB) aliases it.
static const size_t OFF_GI   = 0;
static const size_t OFF_P    = 0;
static const size_t OFF_DL   = OFF_P  + (size_t)32768*16*4;
static const size_t OFF_PSI  = OFF_DL + (size_t)32768*16*4;
static const size_t OFF_B    = (size_t)134217728;
static const size_t OFF_WIH  = OFF_B    + (size_t)33554432;
static const size_t OFF_WQ   = OFF_WIH  + (size_t)1703936;   // 512KB i8 frags
static const size_t OFF_SC   = OFF_WQ   + (size_t)524288;    // 8KB scales
static const size_t OFF_BIAS = OFF_SC   + 8192;
static const size_t OFF_WFC  = OFF_BIAS + 8192;
static const size_t REQUIRED = OFF_WFC  + 256;

// ---------------- K0: pack W_ih (f32 -> bf16 [2048][416]) ----------------
__global__ void k0_pack(const float* __restrict__ wihf, const float* __restrict__ wihb,
                        u16* __restrict__ wih)
{
  int n = blockIdx.x, tid = threadIdx.x;
  const float* src = (n < 1024) ? (wihf + (size_t)n*400) : (wihb + (size_t)(n-1024)*400);
  u32* dst = (u32*)(wih + (size_t)n*416);
  if (tid < 208){
    int j = tid*2;
    u32 v = 0u;
    if (j < 400){
      float2 f = *(const float2*)(src + j);
      v = (u32)f2bf(f.x) | ((u32)f2bf(f.y) << 16);
    }
    dst[tid] = v;
  }
}

// ---------------- K0q: quantize W_hh rows to i8 MFMA fragments ----------------
// wq layout (bytes): dir*262144 + ((((g*16+w)*4+kk)*64 + lq*16 + lr)*16 + e
//   holding W[g*256+w*16+lr][kk*64+lq*16+e].  sc2[row] = rowmax/(127*127).
__global__ __launch_bounds__(256) void k0q(
    const float* __restrict__ whhf, const float* __restrict__ whhb,
    s8* __restrict__ wq, float* __restrict__ sc2)
{
  const int row = blockIdx.x*4 + (threadIdx.x >> 6);
  const int lane = threadIdx.x & 63;
  const float* src = (row < 1024) ? (whhf + (size_t)row*256)
                                  : (whhb + (size_t)(row-1024)*256);
  f32x4 v = *(const f32x4*)(src + lane*4);
  float m = fmaxf(fmaxf(fabsf(v[0]), fabsf(v[1])), fmaxf(fabsf(v[2]), fabsf(v[3])));
  #pragma unroll
  for (int d = 1; d < 64; d <<= 1) m = fmaxf(m, __shfl_xor(m, d, 64));
  float inv = 127.f / (m + 1e-30f);
  u32 pack = 0;
  #pragma unroll
  for (int e = 0; e < 4; e++){
    int q = (int)rintf(v[e]*inv);
    q = q > 127 ? 127 : (q < -127 ? -127 : q);
    pack |= ((u32)(u8)(s8)q) << (8*e);
  }
  const int dir = row >> 10, n = row & 1023;
  const int g = n >> 8, j = n & 255, w2 = j >> 4, lr2 = j & 15;
  const int kk = lane >> 4, lq2 = (lane >> 2) & 3, e4 = lane & 3;
  u32* wq32 = (u32*)wq;
  wq32[dir*65536 + (((g*16 + w2)*4 + kk)*64 + lq2*16 + lr2)*4 + e4] = pack;
  if (lane == 0) sc2[row] = m * (1.f/16129.f);
}

// ---------------- K0b: bias sums (fp32) + wfc = fc_w @ wd ----------------
__global__ void k0_misc(const float* bihf, const float* bhhf, const float* bihb, const float* bhhb,
                        const float* fcw, const float* wdp, float* bias, float* wfc)
{
  int tid = threadIdx.x;
  for (int n = tid; n < 2048; n += 256){
    bias[n] = (n < 1024) ? (bihf[n] + bhhf[n]) : (bihb[n-1024] + bhhb[n-1024]);
  }
  if (tid < 16){
    float s = 0.f;
    for (int k = 0; k < 512; k++) s += fcw[tid*512 + k] * wdp[k];
    wfc[tid] = s;
  }
}

// ---------------- K1: features -> feat[s*64+b][416] bf16 ----------------
__global__ __launch_bounds__(256) void k1_feat(
    const int* __restrict__ X, const int* __restrict__ tg, const int* __restrict__ ch,
    const float* __restrict__ etab, const float* __restrict__ ttab, const float* __restrict__ ctab,
    const float* __restrict__ cw, const float* __restrict__ cb, u16* __restrict__ feat)
{
  const int sb = blockIdx.x, b = blockIdx.y, tid = threadIdx.x;
  __shared__ float ce_s[66*60];
  __shared__ float w_s[150*52];
  for (int i = tid; i < 600; i += 256){
    int wl = i/150, j = i - wl*150;
    int s = sb*4 + wl;
    int idx = X[b*512 + s];
    float2 f = *(const float2*)(etab + (size_t)idx*300 + j*2);
    *(u32*)(feat + (size_t)(s*64 + b)*416 + j*2) = (u32)f2bf(f.x) | ((u32)f2bf(f.y) << 16);
  }
  for (int i = tid; i < 100; i += 256){
    int wl = i/25, j = i - wl*25;
    int s = sb*4 + wl;
    int idx = tg[b*512 + s];
    float2 f = *(const float2*)(ttab + (size_t)idx*50 + j*2);
    *(u32*)(feat + (size_t)(s*64 + b)*416 + 300 + j*2) = (u32)f2bf(f.x) | ((u32)f2bf(f.y) << 16);
  }
  if (tid < 32){
    int wl = tid>>3, j = tid&7;
    int s = sb*4 + wl;
    *(u32*)(feat + (size_t)(s*64 + b)*416 + 400 + j*2) = 0u;
  }
  for (int i = tid; i < 3300; i += 256){
    int qq = i/50, ce = i - qq*50;
    int p = sb*64 - 1 + qq;
    float v = 0.f;
    if (p >= 0 && p < 8192){
      int ci = ch[b*8192 + p];
      v = ctab[ci*50 + ce];
    }
    ce_s[qq*60 + ce] = v;
  }
  for (int i = tid; i < 7500; i += 256){
    int cc = i/150, r2 = i - cc*150;
    int ce = r2/3, dc = r2 - ce*3;
    w_s[(cc*3 + dc)*52 + ce] = cw[i];
  }
  __syncthreads();
  const int li = tid & 15, jg = tid >> 4;
  float acc[4][3];
  #pragma unroll
  for (int k=0;k<4;k++){ acc[k][0]=0.f; acc[k][1]=0.f; acc[k][2]=0.f; }
  #pragma unroll
  for (int dc = 0; dc < 3; dc++){
    for (int ceb = 0; ceb < 48; ceb += 4){
      f32x4 w0 = *(const f32x4*)&w_s[((3*jg+0)*3 + dc)*52 + ceb];
      f32x4 w1 = *(const f32x4*)&w_s[((3*jg+1)*3 + dc)*52 + ceb];
      f32x4 w2 = *(const f32x4*)&w_s[((3*jg+2)*3 + dc)*52 + ceb];
      #pragma unroll
      for (int k = 0; k < 4; k++){
        f32x4 cv = *(const f32x4*)&ce_s[(16*k + li + dc)*60 + ceb];
        #pragma unroll
        for (int e = 0; e < 4; e++){
          acc[k][0] += cv[e]*w0[e];
          acc[k][1] += cv[e]*w1[e];
          acc[k][2] += cv[e]*w2[e];
        }
      }
    }
    float w0a = w_s[((3*jg+0)*3+dc)*52 + 48], w0b = w_s[((3*jg+0)*3+dc)*52 + 49];
    float w1a = w_s[((3*jg+1)*3+dc)*52 + 48], w1b = w_s[((3*jg+1)*3+dc)*52 + 49];
    float w2a = w_s[((3*jg+2)*3+dc)*52 + 48], w2b = w_s[((3*jg+2)*3+dc)*52 + 49];
    #pragma unroll
    for (int k = 0; k < 4; k++){
      float ca = ce_s[(16*k + li + dc)*60 + 48];
      float cb2 = ce_s[(16*k + li + dc)*60 + 49];
      acc[k][0] += ca*w0a + cb2*w0b;
      acc[k][1] += ca*w1a + cb2*w1b;
      acc[k][2] += ca*w2a + cb2*w2b;
    }
  }
  #pragma unroll
  for (int m = 1; m < 16; m <<= 1)
    #pragma unroll
    for (int k=0;k<4;k++)
      #pragma unroll
      for (int c=0;c<3;c++)
        acc[k][c] = fmaxf(acc[k][c], __shfl_xor(acc[k][c], m, 64));
  if (li == 0){
    #pragma unroll
    for (int k=0;k<4;k++)
      #pragma unroll
      for (int c=0;c<3;c++){
        int cc = 3*jg + c;
        int s = sb*4 + k;
        feat[(size_t)(s*64 + b)*416 + 350 + cc] = f2bf(acc[k][c] + cb[cc]);
      }
  }
  if (tid < 128){
    int pl = tid & 63, cc = 48 + (tid >> 6);
    float a2 = 0.f;
    #pragma unroll
    for (int dc = 0; dc < 3; dc++){
      for (int ceb = 0; ceb < 48; ceb += 4){
        f32x4 wv = *(const f32x4*)&w_s[(cc*3 + dc)*52 + ceb];
        f32x4 cv = *(const f32x4*)&ce_s[(pl + dc)*60 + ceb];
        a2 += cv[0]*wv[0] + cv[1]*wv[1] + cv[2]*wv[2] + cv[3]*wv[3];
      }
      a2 += ce_s[(pl+dc)*60 + 48]*w_s[(cc*3+dc)*52 + 48]
          + ce_s[(pl+dc)*60 + 49]*w_s[(cc*3+dc)*52 + 49];
    }
    #pragma unroll
    for (int m = 1; m < 16; m <<= 1) a2 = fmaxf(a2, __shfl_xor(a2, m, 64));
    if ((tid & 15) == 0){
      int s = sb*4 + ((tid & 63) >> 4);
      feat[(size_t)(s*64 + b)*416 + 350 + cc] = f2bf(a2 + cb[cc]);
    }
  }
}

// ---------------- K2: gi = bf16(feat @ wih^T + bias), block-swizzled ----------------
// gi element for (m=s*64+b, n=dir*1024+g*256+j):
//   region (dir*512+s)*4 + (b>>4), u16 idx = tid2*16 + g*4 + (b&3),
//   tid2 = (j>>4)*64 + ((b>>2)&3)*16 + (j&15)
__global__ __launch_bounds__(256) void k2_gemm(
    const u16* __restrict__ featp, const u16* __restrict__ wihp,
    const float* __restrict__ bias, u16* __restrict__ gi)
{
  const int m0 = blockIdx.x*128, n0 = blockIdx.y*128;
  const int tid = threadIdx.x, wv = tid>>6, lane = tid&63;
  const int lr = lane & 15, lq = lane >> 4;
  const int wm = (wv>>1)*64, wn = (wv&1)*64;
  __shared__ u16 As[4096], Bs[4096];
  f32x4 acc[4][4];
  #pragma unroll
  for (int a=0;a<4;a++)
    #pragma unroll
    for (int c=0;c<4;c++) acc[a][c] = (f32x4){0.f,0.f,0.f,0.f};
  for (int k0 = 0; k0 < 416; k0 += 32){
    __syncthreads();
    #pragma unroll
    for (int i = 0; i < 2; i++){
      int c = i*4 + wv;
      gld_lds16(featp + (size_t)(m0 + c*16 + (lane>>2))*416 + k0 + (lane&3)*8, &As[c*512]);
      gld_lds16(wihp  + (size_t)(n0 + c*16 + (lane>>2))*416 + k0 + (lane&3)*8, &Bs[c*512]);
    }
    __syncthreads();
    short8 af[4], bfr[4];
    #pragma unroll
    for (int mt=0; mt<4; mt++) af[mt]  = *(const short8*)(As + (wm + mt*16 + lr)*32 + lq*8);
    #pragma unroll
    for (int nt=0; nt<4; nt++) bfr[nt] = *(const short8*)(Bs + (wn + nt*16 + lr)*32 + lq*8);
    #pragma unroll
    for (int mt=0; mt<4; mt++)
      #pragma unroll
      for (int nt=0; nt<4; nt++)
        acc[mt][nt] = __builtin_amdgcn_mfma_f32_16x16x32_bf16(af[mt], bfr[nt], acc[mt][nt], 0,0,0);
  }
  #pragma unroll
  for (int nt=0; nt<4; nt++){
    const int n = n0 + wn + nt*16 + lr;
    const float bv = bias[n];
    const int dirn = n >> 10, nn = n & 1023;
    const int g = nn >> 8, j = nn & 255, w2 = j >> 4, lr2 = j & 15;
    #pragma unroll
    for (int mt=0; mt<4; mt++)
      #pragma unroll
      for (int r=0; r<4; r++){
        const int m = m0 + wm + mt*16 + lq*4 + r;
        const int s = m >> 6, b = m & 63;
        const int bh = b >> 4, lqb = (b >> 2) & 3, rb = b & 3;
        size_t idx = (((size_t)(dirn*512 + s)*4 + bh) << 14)
                   + (size_t)(w2*64 + lqb*16 + lr2)*16 + g*4 + rb;
        gi[idx] = f2bf(acc[mt][nt][r] + bv);
      }
  }
}

// ---------------- K3: recurrent BiLSTM, batch-split, i8 MFMA, LDS-only ----------------
// 8 blocks x 1024 thr: dir = blk>>2, bh = blk&3 (16 batch rows).
// W_hh i8 frags: kk 0,1 in VGPR (32 regs), kk 2,3 in LDS (128KB).
// h (i8, scale 127) double-buffered in LDS, XOR-swizzled. One __syncthreads/step.
__global__ __launch_bounds__(1024, 1) void k3_lstm(
    const s8* __restrict__ wq, const float* __restrict__ sc2,
    const u16* __restrict__ gi, u16* __restrict__ hcat)
{
  const int dir = blockIdx.x >> 2;
  const int bh  = blockIdx.x & 3;
  const int tid = threadIdx.x;
  const int w = tid >> 6, lane = tid & 63;
  const int lr = lane & 15, lq = lane >> 4;

  __shared__ s8 Bs[131072];      // W frags kk=2,3: [(g*16+w)*2+kx][lane*16]
  __shared__ s8 Hs[2][4096];     // h dbuf [b(16)][256] with col^=(b<<4) swizzle

  const s8* wqd = wq + dir*262144;
  // stage LDS weight half (kk=2,3)
  #pragma unroll
  for (int g = 0; g < 4; g++)
    #pragma unroll
    for (int kx = 0; kx < 2; kx++){
      const s8* gsrc = wqd + ((((g*16 + w)*4 + 2 + kx)*64) << 4) + lane*16;
      gld_lds16(gsrc, &Bs[(((g*16 + w)*2 + kx) << 10)]);
    }
  // VGPR weight half (kk=0,1)
  int4v bq[4][2];
  #pragma unroll
  for (int g = 0; g < 4; g++)
    #pragma unroll
    for (int kk = 0; kk < 2; kk++)
      bq[g][kk] = *(const int4v*)(wqd + (((((g*16 + w)*4 + kk)*64) + lane) << 4));
  // per-gate dequant scales
  float scl[4];
  #pragma unroll
  for (int g = 0; g < 4; g++) scl[g] = sc2[dir*1024 + g*256 + w*16 + lr];
  // zero h buffer 0
  *(u32*)&Hs[0][tid*4] = 0u;

  float cst[4] = {0.f, 0.f, 0.f, 0.f};
  const int j = w*16 + lr;
  __syncthreads();

  #pragma unroll 1
  for (int t = 0; t < 512; t++){
    const int s = dir ? (511 - t) : t;
    // gate-input loads: one contiguous 32B per thread
    const u16* gp = gi + ((((size_t)(dir*512 + s)*4 + bh) << 14) + tid*16);
    ushort8 gva = *(const ushort8*)gp;
    ushort8 gvb = *(const ushort8*)(gp + 8);
    // A fragments (h_{t-1} i8)
    const s8* hb = Hs[t & 1];
    int4v aq[4];
    #pragma unroll
    for (int kk = 0; kk < 4; kk++)
      aq[kk] = *(const int4v*)(hb + lr*256 + ((kk*64 + lq*16) ^ (lr << 4)));
    // MFMA: 4 gates x K=256
    int4v acc[4];
    #pragma unroll
    for (int g = 0; g < 4; g++) acc[g] = (int4v){0,0,0,0};
    #pragma unroll
    for (int g = 0; g < 4; g++)
      acc[g] = __builtin_amdgcn_mfma_i32_16x16x64_i8(aq[0], bq[g][0], acc[g], 0,0,0);
    #pragma unroll
    for (int g = 0; g < 4; g++)
      acc[g] = __builtin_amdgcn_mfma_i32_16x16x64_i8(aq[1], bq[g][1], acc[g], 0,0,0);
    int4v bl[4];
    #pragma unroll
    for (int g = 0; g < 4; g++)
      bl[g] = *(const int4v*)(Bs + ((((g*16 + w)*2 + 0) << 10) + lane*16));
    #pragma unroll
    for (int g = 0; g < 4; g++)
      acc[g] = __builtin_amdgcn_mfma_i32_16x16x64_i8(aq[2], bl[g], acc[g], 0,0,0);
    #pragma unroll
    for (int g = 0; g < 4; g++)
      bl[g] = *(const int4v*)(Bs + ((((g*16 + w)*2 + 1) << 10) + lane*16));
    #pragma unroll
    for (int g = 0; g < 4; g++)
      acc[g] = __builtin_amdgcn_mfma_i32_16x16x64_i8(aq[3], bl[g], acc[g], 0,0,0);
    // cell update: lane owns cells (b = lq*4 + r, j), r=0..3
    s8* hw = Hs[(t + 1) & 1];
    #pragma unroll
    for (int r = 0; r < 4; r++){
      const int b = lq*4 + r;
      float g4[4];
      #pragma unroll
      for (int g = 0; g < 4; g++){
        const int gi16 = g*4 + r;
        u16 raw = (gi16 < 8) ? (u16)gva[gi16] : (u16)gvb[gi16 - 8];
        g4[g] = bf2f(raw) + (float)acc[g][r] * scl[g];
      }
      float iv = sigf(g4[0]), fv = sigf(g4[1]);
      float gg = tanh_f(g4[2]), ov = sigf(g4[3]);
      float c = fv*cst[r] + iv*gg;
      cst[r] = c;
      float h = ov * tanh_f(c);
      hcat[(size_t)(s*64 + bh*16 + b)*512 + dir*256 + j] = f2bf(h);
      int q = (int)rintf(h * 127.f);
      hw[b*256 + (j ^ (b << 4))] = (s8)q;
    }
    __syncthreads();
  }
}

// ---------------- K4: P = Hcat @ fc_w^T + fc_b + lm*wfc  [32768 x 16] fp32 ----------------
__global__ __launch_bounds__(256) void k4_fc(
    const u16* __restrict__ hcat, const float* __restrict__ fcw, const float* __restrict__ fcb,
    const float* __restrict__ lmp, const float* __restrict__ wfc, float* __restrict__ Pout)
{
  const int wv = threadIdx.x >> 6, lane = threadIdx.x & 63;
  const int lr = lane & 15, lq = lane >> 4;
  const int mt = blockIdx.x*4 + wv;
  short8 bfr[16];
  #pragma unroll
  for (int kk = 0; kk < 16; kk++){
    const float* wr = fcw + (size_t)lr*512 + kk*32 + lq*8;
    f32x4 w0 = *(const f32x4*)wr;
    f32x4 w1 = *(const f32x4*)(wr + 4);
    short8 sv;
    #pragma unroll
    for (int e = 0; e < 4; e++){ sv[e] = (short)f2bf(w0[e]); sv[4+e] = (short)f2bf(w1[e]); }
    bfr[kk] = sv;
  }
  f32x4 acc = (f32x4){0.f,0.f,0.f,0.f};
  #pragma unroll
  for (int kk = 0; kk < 16; kk++){
    short8 af = *(const short8*)(hcat + (size_t)(mt*16 + lr)*512 + kk*32 + lq*8);
    acc = __builtin_amdgcn_mfma_f32_16x16x32_bf16(af, bfr[kk], acc, 0,0,0);
  }
  const int cur = lr;
  float fb = fcb[cur];
  float wf = wfc[cur];
  #pragma unroll
  for (int r = 0; r < 4; r++){
    int m = mt*16 + lq*4 + r;
    int b = m & 63, s = m >> 6;
    float lmv = lmp[b*512 + s];
    Pout[(size_t)m*16 + cur] = acc[r] + fb + lmv*wf;
  }
}

// ---------------- K5: Viterbi (one wave per batch element, prefetched) ----------------
__global__ __launch_bounds__(64) void k5_vit(
    const float* __restrict__ Pg, const float* __restrict__ Am,
    float* __restrict__ dout, float* __restrict__ dl, u8* __restrict__ psi)
{
  const int b = blockIdx.x, lane = threadIdx.x;
  const int cur = lane >> 2, q = lane & 3;
  float Ar[4];
  #pragma unroll
  for (int r = 0; r < 4; r++) Ar[r] = Am[(4*q + r)*16 + cur];
  float val = Pg[(size_t)b*16 + cur];
  if (q == 0) dl[(size_t)b*16 + cur] = val;
  float xr[4];
  #pragma unroll
  for (int i = 0; i < 4; i++) xr[i] = Pg[(size_t)((1+i)*64 + b)*16 + cur];
  for (int s = 1; s < 512; s++){
    float x = xr[(s-1)&3];
    if (s + 4 < 512) xr[(s-1)&3] = Pg[(size_t)((s+4)*64 + b)*16 + cur];
    float best = -3.0e38f; int bi = 0;
    #pragma unroll
    for (int r = 0; r < 4; r++){
      float dp = __shfl(val, (4*q + r)*4, 64);
      float sc = (dp + Ar[r]) + x;
      if (sc > best){ best = sc; bi = 4*q + r; }
    }
    #pragma unroll
    for (int m = 1; m <= 2; m <<= 1){
      float ov = __shfl_xor(best, m, 64);
      int   oi = __shfl_xor(bi, m, 64);
      if (ov > best || (ov == best && oi < bi)){ best = ov; bi = oi; }
    }
    val = best;
    if (q == 0){
      dl[(size_t)(s*64 + b)*16 + cur] = best;
      psi[(size_t)(s*64 + b)*16 + cur] = (u8)bi;
    }
  }
  __syncthreads();
  float bv = val; int bix = cur;
  #pragma unroll
  for (int m = 1; m < 64; m <<= 1){
    float ov = __shfl_xor(bv, m, 64);
    int   oi = __shfl_xor(bix, m, 64);
    if (ov > bv || (ov == bv && oi < bix)){ bv = ov; bix = oi; }
  }
  int tag = bix;
  float score = bv;
  if (lane == 0) dout[b*512 + 511] = (float)tag;
  int pvr[4]; float dvr[4];
  #pragma unroll
  for (int i = 0; i < 4; i++){
    if (lane < 16){
      pvr[i] = psi[(size_t)((511-i)*64 + b)*16 + lane];
      dvr[i] = dl[(size_t)((510-i)*64 + b)*16 + lane];
    }
  }
  for (int t = 510; t >= 0; t--){
    const int slot = (510 - t) & 3;
    int pv = pvr[slot]; float dv = dvr[slot];
    if (t >= 4 && lane < 16){
      pvr[slot] = psi[(size_t)((t-3)*64 + b)*16 + lane];
      dvr[slot] = dl[(size_t)((t-4)*64 + b)*16 + lane];
    }
    int prev = __shfl(pv, tag, 64);
    score += __shfl(dv, prev, 64);
    if (lane == 0) dout[b*512 + t] = (float)prev;
    tag = prev;
  }
  if (lane == 0) dout[32768 + b] = score;
}

// ---------------- launcher ----------------
extern "C" void kernel_launch(void* const* d_in, const int* in_sizes, int n_in,
                              void* d_out, int out_size, void* d_ws, size_t ws_size,
                              hipStream_t stream)
{
  (void)in_sizes; (void)n_in; (void)out_size;
  if (ws_size < REQUIRED) return;

  const int*   X    = (const int*)d_in[0];
  const float* lm   = (const float*)d_in[1];
  const int*   tg   = (const int*)d_in[2];
  const int*   ch   = (const int*)d_in[3];
  const float* etab = (const float*)d_in[4];
  const float* ttab = (const float*)d_in[5];
  const float* ctab = (const float*)d_in[6];
  const float* cw   = (const float*)d_in[7];
  const float* cb   = (const float*)d_in[8];
  const float* wihf = (const float*)d_in[9];
  const float* whhf = (const float*)d_in[10];
  const float* bihf = (const float*)d_in[11];
  const float* bhhf = (const float*)d_in[12];
  const float* wihb = (const float*)d_in[13];
  const float* whhb = (const float*)d_in[14];
  const float* bihb = (const float*)d_in[15];
  const float* bhhb = (const float*)d_in[16];
  const float* fcw  = (const float*)d_in[17];
  const float* fcb  = (const float*)d_in[18];
  const float* Am   = (const float*)d_in[19];
  const float* wdp  = (const float*)d_in[20];

  char* ws = (char*)d_ws;
  u16*   gi   = (u16*)(ws + OFF_GI);
  u16*   feat = (u16*)(ws + OFF_B);
  u16*   hcat = (u16*)(ws + OFF_B);
  u16*   wih  = (u16*)(ws + OFF_WIH);
  s8*    wq   = (s8*)(ws + OFF_WQ);
  float* sc2  = (float*)(ws + OFF_SC);
  float* Pg   = (float*)(ws + OFF_P);
  float* dlt  = (float*)(ws + OFF_DL);
  u8*    psi  = (u8*)(ws + OFF_PSI);
  float* bias = (float*)(ws + OFF_BIAS);
  float* wfc  = (float*)(ws + OFF_WFC);
  float* dout = (float*)d_out;

  k0_pack<<<2048, 256, 0, stream>>>(wihf, wihb, wih);
  k0q<<<512, 256, 0, stream>>>(whhf, whhb, wq, sc2);
  k0_misc<<<1, 256, 0, stream>>>(bihf, bhhf, bihb, bhhb, fcw, wdp, bias, wfc);
  k1_feat<<<dim3(128, 64), 256, 0, stream>>>(X, tg, ch, etab, ttab, ctab, cw, cb, feat);
  k2_gemm<<<dim3(256, 16), 256, 0, stream>>>(feat, wih, bias, gi);
  k3_lstm<<<8, 1024, 0, stream>>>(wq, sc2, gi, hcat);
  k4_fc<<<512, 256, 0, stream>>>(hcat, fcw, fcb, lm, wfc, Pg);
  k5_vit<<<64, 64, 0, stream>>>(Pg, Am, dout, dlt, psi);
}

// Round 5
// 1519.328 us; speedup vs baseline: 2.0842x; 1.1836x over previous
//
#include <hip/hip_runtime.h>

// BiLSTM-CRF on MI355X. Round 5: K3 batch-split widened to 32 blocks (4 batch
// rows each), MFMA output redistributed through LDS so cell update is
// 1 cell/thread; gate-input software prefetch; K2 coalesced epilogue restored.

#define DEV __device__ __forceinline__
typedef unsigned short u16;
typedef unsigned int   u32;
typedef unsigned char  u8;
typedef signed char    s8;
using short8  = __attribute__((ext_vector_type(8))) short;
using f32x4   = __attribute__((ext_vector_type(4))) float;
using int4v   = __attribute__((ext_vector_type(4))) int;

DEV float bf2f(u16 u){ union{u32 i; float f;} v; v.i = ((u32)u)<<16; return v.f; }
DEV u16 f2bf(float f){ u32 x = __float_as_uint(f); return (u16)((x + 0x7fffu + ((x>>16)&1u)) >> 16); }
DEV float sigf(float x){ return __builtin_amdgcn_rcpf(1.f + __expf(-x)); }
DEV float tanh_f(float x){ return 1.f - 2.f*__builtin_amdgcn_rcpf(__expf(2.f*x) + 1.f); }

typedef __attribute__((address_space(1))) const u32 GU;
typedef __attribute__((address_space(3))) u32 LU;
DEV void gld_lds16(const void* g, void* l){
  __builtin_amdgcn_global_load_lds((GU*)g, (LU*)l, 16, 0, 0);
}

// ---------------- ws layout (aliased; total ~170MB) ----------------
static const size_t OFF_GI   = 0;
static const size_t OFF_P    = 0;
static const size_t OFF_DL   = OFF_P  + (size_t)32768*16*4;
static const size_t OFF_PSI  = OFF_DL + (size_t)32768*16*4;
static const size_t OFF_B    = (size_t)134217728;
static const size_t OFF_WIH  = OFF_B    + (size_t)33554432;
static const size_t OFF_WQ   = OFF_WIH  + (size_t)1703936;   // 512KB i8 frags
static const size_t OFF_SC   = OFF_WQ   + (size_t)524288;    // 8KB scales
static const size_t OFF_BIAS = OFF_SC   + 8192;
static const size_t OFF_WFC  = OFF_BIAS + 8192;
static const size_t REQUIRED = OFF_WFC  + 256;

// ---------------- K0: pack W_ih (f32 -> bf16 [2048][416]) ----------------
__global__ void k0_pack(const float* __restrict__ wihf, const float* __restrict__ wihb,
                        u16* __restrict__ wih)
{
  int n = blockIdx.x, tid = threadIdx.x;
  const float* src = (n < 1024) ? (wihf + (size_t)n*400) : (wihb + (size_t)(n-1024)*400);
  u32* dst = (u32*)(wih + (size_t)n*416);
  if (tid < 208){
    int j = tid*2;
    u32 v = 0u;
    if (j < 400){
      float2 f = *(const float2*)(src + j);
      v = (u32)f2bf(f.x) | ((u32)f2bf(f.y) << 16);
    }
    dst[tid] = v;
  }
}

// ---------------- K0q: quantize W_hh rows to i8 MFMA fragments ----------------
__global__ __launch_bounds__(256) void k0q(
    const float* __restrict__ whhf, const float* __restrict__ whhb,
    s8* __restrict__ wq, float* __restrict__ sc2)
{
  const int row = blockIdx.x*4 + (threadIdx.x >> 6);
  const int lane = threadIdx.x & 63;
  const float* src = (row < 1024) ? (whhf + (size_t)row*256)
                                  : (whhb + (size_t)(row-1024)*256);
  f32x4 v = *(const f32x4*)(src + lane*4);
  float m = fmaxf(fmaxf(fabsf(v[0]), fabsf(v[1])), fmaxf(fabsf(v[2]), fabsf(v[3])));
  #pragma unroll
  for (int d = 1; d < 64; d <<= 1) m = fmaxf(m, __shfl_xor(m, d, 64));
  float inv = 127.f / (m + 1e-30f);
  u32 pack = 0;
  #pragma unroll
  for (int e = 0; e < 4; e++){
    int q = (int)rintf(v[e]*inv);
    q = q > 127 ? 127 : (q < -127 ? -127 : q);
    pack |= ((u32)(u8)(s8)q) << (8*e);
  }
  const int dir = row >> 10, n = row & 1023;
  const int g = n >> 8, j = n & 255, w2 = j >> 4, lr2 = j & 15;
  const int kk = lane >> 4, lq2 = (lane >> 2) & 3, e4 = lane & 3;
  u32* wq32 = (u32*)wq;
  wq32[dir*65536 + (((g*16 + w2)*4 + kk)*64 + lq2*16 + lr2)*4 + e4] = pack;
  if (lane == 0) sc2[row] = m * (1.f/16129.f);
}

// ---------------- K0b: bias sums (fp32) + wfc = fc_w @ wd (parallel) ----------------
__global__ void k0_misc(const float* bihf, const float* bhhf, const float* bihb, const float* bhhb,
                        const float* fcw, const float* wdp, float* bias, float* wfc)
{
  __shared__ float red[256];
  int tid = threadIdx.x;
  for (int n = tid; n < 2048; n += 256){
    bias[n] = (n < 1024) ? (bihf[n] + bhhf[n]) : (bihb[n-1024] + bhhb[n-1024]);
  }
  const int cur = tid & 15, part = tid >> 4;
  float s = 0.f;
  for (int k = part*32; k < part*32 + 32; k++) s += fcw[cur*512 + k] * wdp[k];
  red[tid] = s;
  __syncthreads();
  if (tid < 16){
    float t = 0.f;
    #pragma unroll
    for (int p = 0; p < 16; p++) t += red[p*16 + tid];
    wfc[tid] = t;
  }
}

// ---------------- K1: features -> feat[s*64+b][416] bf16 ----------------
__global__ __launch_bounds__(256) void k1_feat(
    const int* __restrict__ X, const int* __restrict__ tg, const int* __restrict__ ch,
    const float* __restrict__ etab, const float* __restrict__ ttab, const float* __restrict__ ctab,
    const float* __restrict__ cw, const float* __restrict__ cb, u16* __restrict__ feat)
{
  const int sb = blockIdx.x, b = blockIdx.y, tid = threadIdx.x;
  __shared__ float ce_s[66*60];
  __shared__ float w_s[150*52];
  for (int i = tid; i < 600; i += 256){
    int wl = i/150, j = i - wl*150;
    int s = sb*4 + wl;
    int idx = X[b*512 + s];
    float2 f = *(const float2*)(etab + (size_t)idx*300 + j*2);
    *(u32*)(feat + (size_t)(s*64 + b)*416 + j*2) = (u32)f2bf(f.x) | ((u32)f2bf(f.y) << 16);
  }
  for (int i = tid; i < 100; i += 256){
    int wl = i/25, j = i - wl*25;
    int s = sb*4 + wl;
    int idx = tg[b*512 + s];
    float2 f = *(const float2*)(ttab + (size_t)idx*50 + j*2);
    *(u32*)(feat + (size_t)(s*64 + b)*416 + 300 + j*2) = (u32)f2bf(f.x) | ((u32)f2bf(f.y) << 16);
  }
  if (tid < 32){
    int wl = tid>>3, j = tid&7;
    int s = sb*4 + wl;
    *(u32*)(feat + (size_t)(s*64 + b)*416 + 400 + j*2) = 0u;
  }
  for (int i = tid; i < 3300; i += 256){
    int qq = i/50, ce = i - qq*50;
    int p = sb*64 - 1 + qq;
    float v = 0.f;
    if (p >= 0 && p < 8192){
      int ci = ch[b*8192 + p];
      v = ctab[ci*50 + ce];
    }
    ce_s[qq*60 + ce] = v;
  }
  for (int i = tid; i < 7500; i += 256){
    int cc = i/150, r2 = i - cc*150;
    int ce = r2/3, dc = r2 - ce*3;
    w_s[(cc*3 + dc)*52 + ce] = cw[i];
  }
  __syncthreads();
  const int li = tid & 15, jg = tid >> 4;
  float acc[4][3];
  #pragma unroll
  for (int k=0;k<4;k++){ acc[k][0]=0.f; acc[k][1]=0.f; acc[k][2]=0.f; }
  #pragma unroll
  for (int dc = 0; dc < 3; dc++){
    for (int ceb = 0; ceb < 48; ceb += 4){
      f32x4 w0 = *(const f32x4*)&w_s[((3*jg+0)*3 + dc)*52 + ceb];
      f32x4 w1 = *(const f32x4*)&w_s[((3*jg+1)*3 + dc)*52 + ceb];
      f32x4 w2 = *(const f32x4*)&w_s[((3*jg+2)*3 + dc)*52 + ceb];
      #pragma unroll
      for (int k = 0; k < 4; k++){
        f32x4 cv = *(const f32x4*)&ce_s[(16*k + li + dc)*60 + ceb];
        #pragma unroll
        for (int e = 0; e < 4; e++){
          acc[k][0] += cv[e]*w0[e];
          acc[k][1] += cv[e]*w1[e];
          acc[k][2] += cv[e]*w2[e];
        }
      }
    }
    float w0a = w_s[((3*jg+0)*3+dc)*52 + 48], w0b = w_s[((3*jg+0)*3+dc)*52 + 49];
    float w1a = w_s[((3*jg+1)*3+dc)*52 + 48], w1b = w_s[((3*jg+1)*3+dc)*52 + 49];
    float w2a = w_s[((3*jg+2)*3+dc)*52 + 48], w2b = w_s[((3*jg+2)*3+dc)*52 + 49];
    #pragma unroll
    for (int k = 0; k < 4; k++){
      float ca = ce_s[(16*k + li + dc)*60 + 48];
      float cb2 = ce_s[(16*k + li + dc)*60 + 49];
      acc[k][0] += ca*w0a + cb2*w0b;
      acc[k][1] += ca*w1a + cb2*w1b;
      acc[k][2] += ca*w2a + cb2*w2b;
    }
  }
  #pragma unroll
  for (int m = 1; m < 16; m <<= 1)
    #pragma unroll
    for (int k=0;k<4;k++)
      #pragma unroll
      for (int c=0;c<3;c++)
        acc[k][c] = fmaxf(acc[k][c], __shfl_xor(acc[k][c], m, 64));
  if (li == 0){
    #pragma unroll
    for (int k=0;k<4;k++)
      #pragma unroll
      for (int c=0;c<3;c++){
        int cc = 3*jg + c;
        int s = sb*4 + k;
        feat[(size_t)(s*64 + b)*416 + 350 + cc] = f2bf(acc[k][c] + cb[cc]);
      }
  }
  if (tid < 128){
    int pl = tid & 63, cc = 48 + (tid >> 6);
    float a2 = 0.f;
    #pragma unroll
    for (int dc = 0; dc < 3; dc++){
      for (int ceb = 0; ceb < 48; ceb += 4){
        f32x4 wv = *(const f32x4*)&w_s[(cc*3 + dc)*52 + ceb];
        f32x4 cv = *(const f32x4*)&ce_s[(pl + dc)*60 + ceb];
        a2 += cv[0]*wv[0] + cv[1]*wv[1] + cv[2]*wv[2] + cv[3]*wv[3];
      }
      a2 += ce_s[(pl+dc)*60 + 48]*w_s[(cc*3+dc)*52 + 48]
          + ce_s[(pl+dc)*60 + 49]*w_s[(cc*3+dc)*52 + 49];
    }
    #pragma unroll
    for (int m = 1; m < 16; m <<= 1) a2 = fmaxf(a2, __shfl_xor(a2, m, 64));
    if ((tid & 15) == 0){
      int s = sb*4 + ((tid & 63) >> 4);
      feat[(size_t)(s*64 + b)*416 + 350 + cc] = f2bf(a2 + cb[cc]);
    }
  }
}

// ---------------- K2: gi = bf16(feat @ wih^T + bias)  [32768 x 2048] coalesced ----------------
__global__ __launch_bounds__(256) void k2_gemm(
    const u16* __restrict__ featp, const u16* __restrict__ wihp,
    const float* __restrict__ bias, u16* __restrict__ gi)
{
  const int m0 = blockIdx.x*128, n0 = blockIdx.y*128;
  const int tid = threadIdx.x, wv = tid>>6, lane = tid&63;
  const int lr = lane & 15, lq = lane >> 4;
  const int wm = (wv>>1)*64, wn = (wv&1)*64;
  __shared__ u16 As[4096], Bs[4096];
  f32x4 acc[4][4];
  #pragma unroll
  for (int a=0;a<4;a++)
    #pragma unroll
    for (int c=0;c<4;c++) acc[a][c] = (f32x4){0.f,0.f,0.f,0.f};
  for (int k0 = 0; k0 < 416; k0 += 32){
    __syncthreads();
    #pragma unroll
    for (int i = 0; i < 2; i++){
      int c = i*4 + wv;
      gld_lds16(featp + (size_t)(m0 + c*16 + (lane>>2))*416 + k0 + (lane&3)*8, &As[c*512]);
      gld_lds16(wihp  + (size_t)(n0 + c*16 + (lane>>2))*416 + k0 + (lane&3)*8, &Bs[c*512]);
    }
    __syncthreads();
    short8 af[4], bfr[4];
    #pragma unroll
    for (int mt=0; mt<4; mt++) af[mt]  = *(const short8*)(As + (wm + mt*16 + lr)*32 + lq*8);
    #pragma unroll
    for (int nt=0; nt<4; nt++) bfr[nt] = *(const short8*)(Bs + (wn + nt*16 + lr)*32 + lq*8);
    #pragma unroll
    for (int mt=0; mt<4; mt++)
      #pragma unroll
      for (int nt=0; nt<4; nt++)
        acc[mt][nt] = __builtin_amdgcn_mfma_f32_16x16x32_bf16(af[mt], bfr[nt], acc[mt][nt], 0,0,0);
  }
  #pragma unroll
  for (int nt=0; nt<4; nt++){
    float bv = bias[n0 + wn + nt*16 + lr];
    #pragma unroll
    for (int mt=0; mt<4; mt++)
      #pragma unroll
      for (int r=0; r<4; r++)
        gi[(size_t)(m0 + wm + mt*16 + lq*4 + r)*2048 + n0 + wn + nt*16 + lr]
            = f2bf(acc[mt][nt][r] + bv);
  }
}

// ---------------- K3: recurrent BiLSTM, 32 blocks, i8 MFMA + LDS redistribute ----------------
// dir = blk>>4, batch rows bb = (blk&15)*4. 1024 thr = 16 waves.
// Wave w: j-slice w*16..w*16+15, 4 gates, K=256 (kk0,1 VGPR; kk2,3 LDS).
// MFMA out (valid lq==0 lanes) -> xbuf -> all threads: 1 cell each.
__global__ __launch_bounds__(1024, 1) void k3_lstm(
    const s8* __restrict__ wq, const float* __restrict__ sc2,
    const u16* __restrict__ gi, u16* __restrict__ hcat)
{
  const int dir = blockIdx.x >> 4;
  const int bb  = (blockIdx.x & 15) * 4;
  const int tid = threadIdx.x;
  const int w = tid >> 6, lane = tid & 63;
  const int lr = lane & 15, lq = lane >> 4;

  __shared__ s8 Bs[131072];      // W frags kk=2,3
  __shared__ s8 Hs[2][4096];     // h dbuf [b(16 rows, 4 valid)][256], col^=(b<<4)
  __shared__ float xbuf[4096];   // [b(4)][j(256)][g(4)] pre-activation exchange

  const s8* wqd = wq + dir*262144;
  #pragma unroll
  for (int g = 0; g < 4; g++)
    #pragma unroll
    for (int kx = 0; kx < 2; kx++){
      const s8* gsrc = wqd + ((((g*16 + w)*4 + 2 + kx)*64) << 4) + lane*16;
      gld_lds16(gsrc, &Bs[(((g*16 + w)*2 + kx) << 10)]);
    }
  int4v bq[4][2];
  #pragma unroll
  for (int g = 0; g < 4; g++)
    #pragma unroll
    for (int kk = 0; kk < 2; kk++)
      bq[g][kk] = *(const int4v*)(wqd + (((((g*16 + w)*4 + kk)*64) + lane) << 4));

  // per-thread cell identity
  const int cb = tid >> 8;       // batch row 0..3
  const int cj = tid & 255;      // hidden index
  float scl[4];
  #pragma unroll
  for (int g = 0; g < 4; g++) scl[g] = sc2[dir*1024 + g*256 + cj];

  // zero both h buffers (rows 4..15 stay zero forever)
  *(u32*)&Hs[0][tid*4] = 0u;
  *(u32*)&Hs[1][tid*4] = 0u;

  float cst = 0.f;
  const u16* gth = gi + (size_t)dir*1024 + cj;   // + m*2048 + g*256
  u32 gcur[4], gnxt[4];
  {
    const int s0 = dir ? 511 : 0;
    const size_t mrow = (size_t)(s0*64 + bb + cb)*2048;
    #pragma unroll
    for (int g = 0; g < 4; g++) gcur[g] = gth[mrow + g*256];
  }
  __syncthreads();

  #pragma unroll 1
  for (int t = 0; t < 512; t++){
    const int s = dir ? (511 - t) : t;
    const int sn = (t < 511) ? (dir ? s - 1 : s + 1) : s;
    // prefetch next step's gate inputs (used next iteration)
    {
      const size_t mrow = (size_t)(sn*64 + bb + cb)*2048;
      #pragma unroll
      for (int g = 0; g < 4; g++) gnxt[g] = gth[mrow + g*256];
    }
    // MFMA phase
    const s8* hb = Hs[t & 1];
    int4v aq[4];
    #pragma unroll
    for (int kk = 0; kk < 4; kk++)
      aq[kk] = *(const int4v*)(hb + lr*256 + ((kk*64 + lq*16) ^ (lr << 4)));
    int4v acc[4];
    #pragma unroll
    for (int g = 0; g < 4; g++) acc[g] = (int4v){0,0,0,0};
    #pragma unroll
    for (int g = 0; g < 4; g++)
      acc[g] = __builtin_amdgcn_mfma_i32_16x16x64_i8(aq[0], bq[g][0], acc[g], 0,0,0);
    #pragma unroll
    for (int g = 0; g < 4; g++)
      acc[g] = __builtin_amdgcn_mfma_i32_16x16x64_i8(aq[1], bq[g][1], acc[g], 0,0,0);
    int4v bl[4];
    #pragma unroll
    for (int g = 0; g < 4; g++)
      bl[g] = *(const int4v*)(Bs + ((((g*16 + w)*2 + 0) << 10) + lane*16));
    #pragma unroll
    for (int g = 0; g < 4; g++)
      acc[g] = __builtin_amdgcn_mfma_i32_16x16x64_i8(aq[2], bl[g], acc[g], 0,0,0);
    #pragma unroll
    for (int g = 0; g < 4; g++)
      bl[g] = *(const int4v*)(Bs + ((((g*16 + w)*2 + 1) << 10) + lane*16));
    #pragma unroll
    for (int g = 0; g < 4; g++)
      acc[g] = __builtin_amdgcn_mfma_i32_16x16x64_i8(aq[3], bl[g], acc[g], 0,0,0);
    // redistribute: valid rows b = r (lq==0) -> xbuf[b][j][g]
    if (lq == 0){
      const int j = w*16 + lr;
      #pragma unroll
      for (int r = 0; r < 4; r++){
        f32x4 v = (f32x4){(float)acc[0][r], (float)acc[1][r], (float)acc[2][r], (float)acc[3][r]};
        *(f32x4*)&xbuf[(r*256 + j)*4] = v;
      }
    }
    __syncthreads();
    // cell update: 1 cell per thread (cb, cj)
    f32x4 p = *(const f32x4*)&xbuf[(cb*256 + cj)*4];
    float g4[4];
    #pragma unroll
    for (int g = 0; g < 4; g++) g4[g] = bf2f((u16)gcur[g]) + p[g]*scl[g];
    float iv = sigf(g4[0]), fv = sigf(g4[1]);
    float gg = tanh_f(g4[2]), ov = sigf(g4[3]);
    float c = fv*cst + iv*gg;
    cst = c;
    float h = ov * tanh_f(c);
    hcat[(size_t)(s*64 + bb + cb)*512 + dir*256 + cj] = f2bf(h);
    int q = (int)rintf(h * 127.f);
    Hs[(t + 1) & 1][cb*256 + (cj ^ (cb << 4))] = (s8)q;
    #pragma unroll
    for (int g = 0; g < 4; g++) gcur[g] = gnxt[g];
    __syncthreads();
  }
}

// ---------------- K4: P = Hcat @ fc_w^T + fc_b + lm*wfc  [32768 x 16] fp32 ----------------
__global__ __launch_bounds__(256) void k4_fc(
    const u16* __restrict__ hcat, const float* __restrict__ fcw, const float* __restrict__ fcb,
    const float* __restrict__ lmp, const float* __restrict__ wfc, float* __restrict__ Pout)
{
  const int wv = threadIdx.x >> 6, lane = threadIdx.x & 63;
  const int lr = lane & 15, lq = lane >> 4;
  const int mt = blockIdx.x*4 + wv;
  short8 bfr[16];
  #pragma unroll
  for (int kk = 0; kk < 16; kk++){
    const float* wr = fcw + (size_t)lr*512 + kk*32 + lq*8;
    f32x4 w0 = *(const f32x4*)wr;
    f32x4 w1 = *(const f32x4*)(wr + 4);
    short8 sv;
    #pragma unroll
    for (int e = 0; e < 4; e++){ sv[e] = (short)f2bf(w0[e]); sv[4+e] = (short)f2bf(w1[e]); }
    bfr[kk] = sv;
  }
  f32x4 acc = (f32x4){0.f,0.f,0.f,0.f};
  #pragma unroll
  for (int kk = 0; kk < 16; kk++){
    short8 af = *(const short8*)(hcat + (size_t)(mt*16 + lr)*512 + kk*32 + lq*8);
    acc = __builtin_amdgcn_mfma_f32_16x16x32_bf16(af, bfr[kk], acc, 0,0,0);
  }
  const int cur = lr;
  float fb = fcb[cur];
  float wf = wfc[cur];
  #pragma unroll
  for (int r = 0; r < 4; r++){
    int m = mt*16 + lq*4 + r;
    int b = m & 63, s = m >> 6;
    float lmv = lmp[b*512 + s];
    Pout[(size_t)m*16 + cur] = acc[r] + fb + lmv*wf;
  }
}

// ---------------- K5: Viterbi (one wave per batch element, prefetched) ----------------
__global__ __launch_bounds__(64) void k5_vit(
    const float* __restrict__ Pg, const float* __restrict__ Am,
    float* __restrict__ dout, float* __restrict__ dl, u8* __restrict__ psi)
{
  const int b = blockIdx.x, lane = threadIdx.x;
  const int cur = lane >> 2, q = lane & 3;
  float Ar[4];
  #pragma unroll
  for (int r = 0; r < 4; r++) Ar[r] = Am[(4*q + r)*16 + cur];
  float val = Pg[(size_t)b*16 + cur];
  if (q == 0) dl[(size_t)b*16 + cur] = val;
  float xr[4];
  #pragma unroll
  for (int i = 0; i < 4; i++) xr[i] = Pg[(size_t)((1+i)*64 + b)*16 + cur];
  for (int s = 1; s < 512; s++){
    float x = xr[(s-1)&3];
    if (s + 4 < 512) xr[(s-1)&3] = Pg[(size_t)((s+4)*64 + b)*16 + cur];
    float best = -3.0e38f; int bi = 0;
    #pragma unroll
    for (int r = 0; r < 4; r++){
      float dp = __shfl(val, (4*q + r)*4, 64);
      float sc = (dp + Ar[r]) + x;
      if (sc > best){ best = sc; bi = 4*q + r; }
    }
    #pragma unroll
    for (int m = 1; m <= 2; m <<= 1){
      float ov = __shfl_xor(best, m, 64);
      int   oi = __shfl_xor(bi, m, 64);
      if (ov > best || (ov == best && oi < bi)){ best = ov; bi = oi; }
    }
    val = best;
    if (q == 0){
      dl[(size_t)(s*64 + b)*16 + cur] = best;
      psi[(size_t)(s*64 + b)*16 + cur] = (u8)bi;
    }
  }
  __syncthreads();
  float bv = val; int bix = cur;
  #pragma unroll
  for (int m = 1; m < 64; m <<= 1){
    float ov = __shfl_xor(bv, m, 64);
    int   oi = __shfl_xor(bix, m, 64);
    if (ov > bv || (ov == bv && oi < bix)){ bv = ov; bix = oi; }
  }
  int tag = bix;
  float score = bv;
  if (lane == 0) dout[b*512 + 511] = (float)tag;
  int pvr[4]; float dvr[4];
  #pragma unroll
  for (int i = 0; i < 4; i++){
    if (lane < 16){
      pvr[i] = psi[(size_t)((511-i)*64 + b)*16 + lane];
      dvr[i] = dl[(size_t)((510-i)*64 + b)*16 + lane];
    }
  }
  for (int t = 510; t >= 0; t--){
    const int slot = (510 - t) & 3;
    int pv = pvr[slot]; float dv = dvr[slot];
    if (t >= 4 && lane < 16){
      pvr[slot] = psi[(size_t)((t-3)*64 + b)*16 + lane];
      dvr[slot] = dl[(size_t)((t-4)*64 + b)*16 + lane];
    }
    int prev = __shfl(pv, tag, 64);
    score += __shfl(dv, prev, 64);
    if (lane == 0) dout[b*512 + t] = (float)prev;
    tag = prev;
  }
  if (lane == 0) dout[32768 + b] = score;
}

// ---------------- launcher ----------------
extern "C" void kernel_launch(void* const* d_in, const int* in_sizes, int n_in,
                              void* d_out, int out_size, void* d_ws, size_t ws_size,
                              hipStream_t stream)
{
  (void)in_sizes; (void)n_in; (void)out_size;
  if (ws_size < REQUIRED) return;

  const int*   X    = (const int*)d_in[0];
  const float* lm   = (const float*)d_in[1];
  const int*   tg   = (const int*)d_in[2];
  const int*   ch   = (const int*)d_in[3];
  const float* etab = (const float*)d_in[4];
  const float* ttab = (const float*)d_in[5];
  const float* ctab = (const float*)d_in[6];
  const float* cw   = (const float*)d_in[7];
  const float* cb   = (const float*)d_in[8];
  const float* wihf = (const float*)d_in[9];
  const float* whhf = (const float*)d_in[10];
  const float* bihf = (const float*)d_in[11];
  const float* bhhf = (const float*)d_in[12];
  const float* wihb = (const float*)d_in[13];
  const float* whhb = (const float*)d_in[14];
  const float* bihb = (const float*)d_in[15];
  const float* bhhb = (const float*)d_in[16];
  const float* fcw  = (const float*)d_in[17];
  const float* fcb  = (const float*)d_in[18];
  const float* Am   = (const float*)d_in[19];
  const float* wdp  = (const float*)d_in[20];

  char* ws = (char*)d_ws;
  u16*   gi   = (u16*)(ws + OFF_GI);
  u16*   feat = (u16*)(ws + OFF_B);
  u16*   hcat = (u16*)(ws + OFF_B);
  u16*   wih  = (u16*)(ws + OFF_WIH);
  s8*    wq   = (s8*)(ws + OFF_WQ);
  float* sc2  = (float*)(ws + OFF_SC);
  float* Pg   = (float*)(ws + OFF_P);
  float* dlt  = (float*)(ws + OFF_DL);
  u8*    psi  = (u8*)(ws + OFF_PSI);
  float* bias = (float*)(ws + OFF_BIAS);
  float* wfc  = (float*)(ws + OFF_WFC);
  float* dout = (float*)d_out;

  k0_pack<<<2048, 256, 0, stream>>>(wihf, wihb, wih);
  k0q<<<512, 256, 0, stream>>>(whhf, whhb, wq, sc2);
  k0_misc<<<1, 256, 0, stream>>>(bihf, bhhf, bihb, bhhb, fcw, wdp, bias, wfc);
  k1_feat<<<dim3(128, 64), 256, 0, stream>>>(X, tg, ch, etab, ttab, ctab, cw, cb, feat);
  k2_gemm<<<dim3(256, 16), 256, 0, stream>>>(feat, wih, bias, gi);
  k3_lstm<<<32, 1024, 0, stream>>>(wq, sc2, gi, hcat);
  k4_fc<<<512, 256, 0, stream>>>(hcat, fcw, fcb, lm, wfc, Pg);
  k5_vit<<<64, 64, 0, stream>>>(Pg, Am, dout, dlt, psi);
}

// Round 6
// 1384.718 us; speedup vs baseline: 2.2868x; 1.0972x over previous
//
#include <hip/hip_runtime.h>

// BiLSTM-CRF on MI355X. Round 6: K3 batch-split widened to 64 blocks (2 batch
// rows each, 512 thr, wave owns 2 j-slices), lgkm-only in-loop barriers.

#define DEV __device__ __forceinline__
typedef unsigned short u16;
typedef unsigned int   u32;
typedef unsigned char  u8;
typedef signed char    s8;
using short8  = __attribute__((ext_vector_type(8))) short;
using f32x4   = __attribute__((ext_vector_type(4))) float;
using int4v   = __attribute__((ext_vector_type(4))) int;

DEV float bf2f(u16 u){ union{u32 i; float f;} v; v.i = ((u32)u)<<16; return v.f; }
DEV u16 f2bf(float f){ u32 x = __float_as_uint(f); return (u16)((x + 0x7fffu + ((x>>16)&1u)) >> 16); }
DEV float sigf(float x){ return __builtin_amdgcn_rcpf(1.f + __expf(-x)); }
DEV float tanh_f(float x){ return 1.f - 2.f*__builtin_amdgcn_rcpf(__expf(2.f*x) + 1.f); }

typedef __attribute__((address_space(1))) const u32 GU;
typedef __attribute__((address_space(3))) u32 LU;
DEV void gld_lds16(const void* g, void* l){
  __builtin_amdgcn_global_load_lds((GU*)g, (LU*)l, 16, 0, 0);
}
// LDS-only barrier: no vmcnt drain (global stores/prefetch float across)
DEV void bar_l(){
  __builtin_amdgcn_sched_barrier(0);
  asm volatile("s_waitcnt lgkmcnt(0)" ::: "memory");
  __builtin_amdgcn_s_barrier();
  __builtin_amdgcn_sched_barrier(0);
}

// ---------------- ws layout (aliased; total ~170MB) ----------------
static const size_t OFF_GI   = 0;
static const size_t OFF_P    = 0;
static const size_t OFF_DL   = OFF_P  + (size_t)32768*16*4;
static const size_t OFF_PSI  = OFF_DL + (size_t)32768*16*4;
static const size_t OFF_B    = (size_t)134217728;
static const size_t OFF_WIH  = OFF_B    + (size_t)33554432;
static const size_t OFF_WQ   = OFF_WIH  + (size_t)1703936;   // 512KB i8 frags
static const size_t OFF_SC   = OFF_WQ   + (size_t)524288;    // 8KB scales
static const size_t OFF_BIAS = OFF_SC   + 8192;
static const size_t OFF_WFC  = OFF_BIAS + 8192;
static const size_t REQUIRED = OFF_WFC  + 256;

// ---------------- K0: pack W_ih (f32 -> bf16 [2048][416]) ----------------
__global__ void k0_pack(const float* __restrict__ wihf, const float* __restrict__ wihb,
                        u16* __restrict__ wih)
{
  int n = blockIdx.x, tid = threadIdx.x;
  const float* src = (n < 1024) ? (wihf + (size_t)n*400) : (wihb + (size_t)(n-1024)*400);
  u32* dst = (u32*)(wih + (size_t)n*416);
  if (tid < 208){
    int j = tid*2;
    u32 v = 0u;
    if (j < 400){
      float2 f = *(const float2*)(src + j);
      v = (u32)f2bf(f.x) | ((u32)f2bf(f.y) << 16);
    }
    dst[tid] = v;
  }
}

// ---------------- K0q: quantize W_hh rows to i8 MFMA fragments ----------------
__global__ __launch_bounds__(256) void k0q(
    const float* __restrict__ whhf, const float* __restrict__ whhb,
    s8* __restrict__ wq, float* __restrict__ sc2)
{
  const int row = blockIdx.x*4 + (threadIdx.x >> 6);
  const int lane = threadIdx.x & 63;
  const float* src = (row < 1024) ? (whhf + (size_t)row*256)
                                  : (whhb + (size_t)(row-1024)*256);
  f32x4 v = *(const f32x4*)(src + lane*4);
  float m = fmaxf(fmaxf(fabsf(v[0]), fabsf(v[1])), fmaxf(fabsf(v[2]), fabsf(v[3])));
  #pragma unroll
  for (int d = 1; d < 64; d <<= 1) m = fmaxf(m, __shfl_xor(m, d, 64));
  float inv = 127.f / (m + 1e-30f);
  u32 pack = 0;
  #pragma unroll
  for (int e = 0; e < 4; e++){
    int q = (int)rintf(v[e]*inv);
    q = q > 127 ? 127 : (q < -127 ? -127 : q);
    pack |= ((u32)(u8)(s8)q) << (8*e);
  }
  const int dir = row >> 10, n = row & 1023;
  const int g = n >> 8, j = n & 255, w2 = j >> 4, lr2 = j & 15;
  const int kk = lane >> 4, lq2 = (lane >> 2) & 3, e4 = lane & 3;
  u32* wq32 = (u32*)wq;
  wq32[dir*65536 + (((g*16 + w2)*4 + kk)*64 + lq2*16 + lr2)*4 + e4] = pack;
  if (lane == 0) sc2[row] = m * (1.f/16129.f);
}

// ---------------- K0b: bias sums (fp32) + wfc = fc_w @ wd (parallel) ----------------
__global__ void k0_misc(const float* bihf, const float* bhhf, const float* bihb, const float* bhhb,
                        const float* fcw, const float* wdp, float* bias, float* wfc)
{
  __shared__ float red[256];
  int tid = threadIdx.x;
  for (int n = tid; n < 2048; n += 256){
    bias[n] = (n < 1024) ? (bihf[n] + bhhf[n]) : (bihb[n-1024] + bhhb[n-1024]);
  }
  const int cur = tid & 15, part = tid >> 4;
  float s = 0.f;
  for (int k = part*32; k < part*32 + 32; k++) s += fcw[cur*512 + k] * wdp[k];
  red[tid] = s;
  __syncthreads();
  if (tid < 16){
    float t = 0.f;
    #pragma unroll
    for (int p = 0; p < 16; p++) t += red[p*16 + tid];
    wfc[tid] = t;
  }
}

// ---------------- K1: features -> feat[s*64+b][416] bf16 ----------------
__global__ __launch_bounds__(256) void k1_feat(
    const int* __restrict__ X, const int* __restrict__ tg, const int* __restrict__ ch,
    const float* __restrict__ etab, const float* __restrict__ ttab, const float* __restrict__ ctab,
    const float* __restrict__ cw, const float* __restrict__ cb, u16* __restrict__ feat)
{
  const int sb = blockIdx.x, b = blockIdx.y, tid = threadIdx.x;
  __shared__ float ce_s[66*60];
  __shared__ float w_s[150*52];
  for (int i = tid; i < 600; i += 256){
    int wl = i/150, j = i - wl*150;
    int s = sb*4 + wl;
    int idx = X[b*512 + s];
    float2 f = *(const float2*)(etab + (size_t)idx*300 + j*2);
    *(u32*)(feat + (size_t)(s*64 + b)*416 + j*2) = (u32)f2bf(f.x) | ((u32)f2bf(f.y) << 16);
  }
  for (int i = tid; i < 100; i += 256){
    int wl = i/25, j = i - wl*25;
    int s = sb*4 + wl;
    int idx = tg[b*512 + s];
    float2 f = *(const float2*)(ttab + (size_t)idx*50 + j*2);
    *(u32*)(feat + (size_t)(s*64 + b)*416 + 300 + j*2) = (u32)f2bf(f.x) | ((u32)f2bf(f.y) << 16);
  }
  if (tid < 32){
    int wl = tid>>3, j = tid&7;
    int s = sb*4 + wl;
    *(u32*)(feat + (size_t)(s*64 + b)*416 + 400 + j*2) = 0u;
  }
  for (int i = tid; i < 3300; i += 256){
    int qq = i/50, ce = i - qq*50;
    int p = sb*64 - 1 + qq;
    float v = 0.f;
    if (p >= 0 && p < 8192){
      int ci = ch[b*8192 + p];
      v = ctab[ci*50 + ce];
    }
    ce_s[qq*60 + ce] = v;
  }
  for (int i = tid; i < 7500; i += 256){
    int cc = i/150, r2 = i - cc*150;
    int ce = r2/3, dc = r2 - ce*3;
    w_s[(cc*3 + dc)*52 + ce] = cw[i];
  }
  __syncthreads();
  const int li = tid & 15, jg = tid >> 4;
  float acc[4][3];
  #pragma unroll
  for (int k=0;k<4;k++){ acc[k][0]=0.f; acc[k][1]=0.f; acc[k][2]=0.f; }
  #pragma unroll
  for (int dc = 0; dc < 3; dc++){
    for (int ceb = 0; ceb < 48; ceb += 4){
      f32x4 w0 = *(const f32x4*)&w_s[((3*jg+0)*3 + dc)*52 + ceb];
      f32x4 w1 = *(const f32x4*)&w_s[((3*jg+1)*3 + dc)*52 + ceb];
      f32x4 w2 = *(const f32x4*)&w_s[((3*jg+2)*3 + dc)*52 + ceb];
      #pragma unroll
      for (int k = 0; k < 4; k++){
        f32x4 cv = *(const f32x4*)&ce_s[(16*k + li + dc)*60 + ceb];
        #pragma unroll
        for (int e = 0; e < 4; e++){
          acc[k][0] += cv[e]*w0[e];
          acc[k][1] += cv[e]*w1[e];
          acc[k][2] += cv[e]*w2[e];
        }
      }
    }
    float w0a = w_s[((3*jg+0)*3+dc)*52 + 48], w0b = w_s[((3*jg+0)*3+dc)*52 + 49];
    float w1a = w_s[((3*jg+1)*3+dc)*52 + 48], w1b = w_s[((3*jg+1)*3+dc)*52 + 49];
    float w2a = w_s[((3*jg+2)*3+dc)*52 + 48], w2b = w_s[((3*jg+2)*3+dc)*52 + 49];
    #pragma unroll
    for (int k = 0; k < 4; k++){
      float ca = ce_s[(16*k + li + dc)*60 + 48];
      float cb2 = ce_s[(16*k + li + dc)*60 + 49];
      acc[k][0] += ca*w0a + cb2*w0b;
      acc[k][1] += ca*w1a + cb2*w1b;
      acc[k][2] += ca*w2a + cb2*w2b;
    }
  }
  #pragma unroll
  for (int m = 1; m < 16; m <<= 1)
    #pragma unroll
    for (int k=0;k<4;k++)
      #pragma unroll
      for (int c=0;c<3;c++)
        acc[k][c] = fmaxf(acc[k][c], __shfl_xor(acc[k][c], m, 64));
  if (li == 0){
    #pragma unroll
    for (int k=0;k<4;k++)
      #pragma unroll
      for (int c=0;c<3;c++){
        int cc = 3*jg + c;
        int s = sb*4 + k;
        feat[(size_t)(s*64 + b)*416 + 350 + cc] = f2bf(acc[k][c] + cb[cc]);
      }
  }
  if (tid < 128){
    int pl = tid & 63, cc = 48 + (tid >> 6);
    float a2 = 0.f;
    #pragma unroll
    for (int dc = 0; dc < 3; dc++){
      for (int ceb = 0; ceb < 48; ceb += 4){
        f32x4 wv = *(const f32x4*)&w_s[(cc*3 + dc)*52 + ceb];
        f32x4 cv = *(const f32x4*)&ce_s[(pl + dc)*60 + ceb];
        a2 += cv[0]*wv[0] + cv[1]*wv[1] + cv[2]*wv[2] + cv[3]*wv[3];
      }
      a2 += ce_s[(pl+dc)*60 + 48]*w_s[(cc*3+dc)*52 + 48]
          + ce_s[(pl+dc)*60 + 49]*w_s[(cc*3+dc)*52 + 49];
    }
    #pragma unroll
    for (int m = 1; m < 16; m <<= 1) a2 = fmaxf(a2, __shfl_xor(a2, m, 64));
    if ((tid & 15) == 0){
      int s = sb*4 + ((tid & 63) >> 4);
      feat[(size_t)(s*64 + b)*416 + 350 + cc] = f2bf(a2 + cb[cc]);
    }
  }
}

// ---------------- K2: gi = bf16(feat @ wih^T + bias)  [32768 x 2048] ----------------
__global__ __launch_bounds__(256) void k2_gemm(
    const u16* __restrict__ featp, const u16* __restrict__ wihp,
    const float* __restrict__ bias, u16* __restrict__ gi)
{
  const int m0 = blockIdx.x*128, n0 = blockIdx.y*128;
  const int tid = threadIdx.x, wv = tid>>6, lane = tid&63;
  const int lr = lane & 15, lq = lane >> 4;
  const int wm = (wv>>1)*64, wn = (wv&1)*64;
  __shared__ u16 As[4096], Bs[4096];
  f32x4 acc[4][4];
  #pragma unroll
  for (int a=0;a<4;a++)
    #pragma unroll
    for (int c=0;c<4;c++) acc[a][c] = (f32x4){0.f,0.f,0.f,0.f};
  for (int k0 = 0; k0 < 416; k0 += 32){
    __syncthreads();
    #pragma unroll
    for (int i = 0; i < 2; i++){
      int c = i*4 + wv;
      gld_lds16(featp + (size_t)(m0 + c*16 + (lane>>2))*416 + k0 + (lane&3)*8, &As[c*512]);
      gld_lds16(wihp  + (size_t)(n0 + c*16 + (lane>>2))*416 + k0 + (lane&3)*8, &Bs[c*512]);
    }
    __syncthreads();
    short8 af[4], bfr[4];
    #pragma unroll
    for (int mt=0; mt<4; mt++) af[mt]  = *(const short8*)(As + (wm + mt*16 + lr)*32 + lq*8);
    #pragma unroll
    for (int nt=0; nt<4; nt++) bfr[nt] = *(const short8*)(Bs + (wn + nt*16 + lr)*32 + lq*8);
    #pragma unroll
    for (int mt=0; mt<4; mt++)
      #pragma unroll
      for (int nt=0; nt<4; nt++)
        acc[mt][nt] = __builtin_amdgcn_mfma_f32_16x16x32_bf16(af[mt], bfr[nt], acc[mt][nt], 0,0,0);
  }
  #pragma unroll
  for (int nt=0; nt<4; nt++){
    float bv = bias[n0 + wn + nt*16 + lr];
    #pragma unroll
    for (int mt=0; mt<4; mt++)
      #pragma unroll
      for (int r=0; r<4; r++)
        gi[(size_t)(m0 + wm + mt*16 + lq*4 + r)*2048 + n0 + wn + nt*16 + lr]
            = f2bf(acc[mt][nt][r] + bv);
  }
}

// ---------------- K3: recurrent BiLSTM, 64 blocks x 512 thr, i8 MFMA ----------------
// dir = blk>>5, batch rows bb = (blk&31)*2. 8 waves; wave w owns j-slices 2w,2w+1.
// W_hh i8: kk0-1 VGPR (64 regs), kk2-3 LDS (128KB). h dbuf LDS. lgkm-only barriers.
__global__ __launch_bounds__(512, 1) void k3_lstm(
    const s8* __restrict__ wq, const float* __restrict__ sc2,
    const u16* __restrict__ gi, u16* __restrict__ hcat)
{
  const int dir = blockIdx.x >> 5;
  const int bb  = (blockIdx.x & 31) * 2;
  const int tid = threadIdx.x;
  const int w = tid >> 6, lane = tid & 63;
  const int lr = lane & 15, lq = lane >> 4;
  const int cb = tid >> 8, cj = tid & 255;   // cell identity (batch row, hidden j)

  __shared__ s8 Bs[131072];      // W frags kk=2,3 for all 16 slices
  __shared__ s8 Hs[2][4096];     // h dbuf [16 rows (2 valid)][256], col^=(b<<4)
  __shared__ float xbuf[2048];   // [2][256][4] pre-activation exchange

  const s8* wqd = wq + dir*262144;
  #pragma unroll
  for (int sl = 0; sl < 2; sl++)
    #pragma unroll
    for (int g = 0; g < 4; g++)
      #pragma unroll
      for (int kx = 0; kx < 2; kx++){
        const int s2 = 2*w + sl;
        const s8* gsrc = wqd + ((((g*16 + s2)*4 + 2 + kx)*64) << 4) + lane*16;
        gld_lds16(gsrc, &Bs[(((g*16 + s2)*2 + kx) << 10)]);
      }
  int4v bq[2][4][2];
  #pragma unroll
  for (int sl = 0; sl < 2; sl++)
    #pragma unroll
    for (int g = 0; g < 4; g++)
      #pragma unroll
      for (int kk = 0; kk < 2; kk++)
        bq[sl][g][kk] = *(const int4v*)(wqd + (((((g*16 + 2*w + sl)*4 + kk)*64) + lane) << 4));

  float scl[4];
  #pragma unroll
  for (int g = 0; g < 4; g++) scl[g] = sc2[dir*1024 + g*256 + cj];

  // zero both h buffers (rows 2..15 stay zero forever)
  *(uint2*)&Hs[0][tid*8] = (uint2){0u,0u};
  *(uint2*)&Hs[1][tid*8] = (uint2){0u,0u};

  float cst = 0.f;
  const u16* gp;
  {
    const int s0i = dir ? 511 : 0;
    gp = gi + (size_t)(s0i*64 + bb + cb)*2048 + dir*1024 + cj;
  }
  const ptrdiff_t dstep = dir ? -(ptrdiff_t)131072 : (ptrdiff_t)131072;  // +-64*2048
  u32 gcur[4], gnxt[4];
  #pragma unroll
  for (int g = 0; g < 4; g++) gcur[g] = gp[g*256];
  __syncthreads();   // full barrier: weight staging (vmcnt) + Hs zero

  #pragma unroll 1
  for (int t = 0; t < 512; t++){
    const int s = dir ? (511 - t) : t;
    // prefetch next step's gate inputs
    const u16* gq = (t < 511) ? (gp + dstep) : gp;
    #pragma unroll
    for (int g = 0; g < 4; g++) gnxt[g] = gq[g*256];
    // MFMA phase
    const s8* hb = Hs[t & 1];
    int4v aq[4];
    #pragma unroll
    for (int kk = 0; kk < 4; kk++)
      aq[kk] = *(const int4v*)(hb + lr*256 + ((kk*64 + lq*16) ^ (lr << 4)));
    int4v acc[2][4];
    #pragma unroll
    for (int sl = 0; sl < 2; sl++)
      #pragma unroll
      for (int g = 0; g < 4; g++) acc[sl][g] = (int4v){0,0,0,0};
    #pragma unroll
    for (int kk = 0; kk < 2; kk++)
      #pragma unroll
      for (int sl = 0; sl < 2; sl++)
        #pragma unroll
        for (int g = 0; g < 4; g++)
          acc[sl][g] = __builtin_amdgcn_mfma_i32_16x16x64_i8(aq[kk], bq[sl][g][kk], acc[sl][g], 0,0,0);
    #pragma unroll
    for (int kx = 0; kx < 2; kx++){
      int4v bl[2][4];
      #pragma unroll
      for (int sl = 0; sl < 2; sl++)
        #pragma unroll
        for (int g = 0; g < 4; g++)
          bl[sl][g] = *(const int4v*)(Bs + ((((g*16 + 2*w + sl)*2 + kx) << 10) + lane*16));
      #pragma unroll
      for (int sl = 0; sl < 2; sl++)
        #pragma unroll
        for (int g = 0; g < 4; g++)
          acc[sl][g] = __builtin_amdgcn_mfma_i32_16x16x64_i8(aq[2+kx], bl[sl][g], acc[sl][g], 0,0,0);
    }
    // redistribute: valid rows r=0,1 (lq==0 lanes) -> xbuf[r][j][g]
    if (lq == 0){
      #pragma unroll
      for (int sl = 0; sl < 2; sl++){
        const int j = (2*w + sl)*16 + lr;
        #pragma unroll
        for (int r = 0; r < 2; r++){
          f32x4 v = (f32x4){(float)acc[sl][0][r], (float)acc[sl][1][r],
                            (float)acc[sl][2][r], (float)acc[sl][3][r]};
          *(f32x4*)&xbuf[(r*256 + j)*4] = v;
        }
      }
    }
    bar_l();
    // cell update: 1 cell per thread (cb, cj); xbuf index (cb*256+cj) == tid
    f32x4 p = *(const f32x4*)&xbuf[tid*4];
    float g4[4];
    #pragma unroll
    for (int g = 0; g < 4; g++) g4[g] = bf2f((u16)gcur[g]) + p[g]*scl[g];
    float iv = sigf(g4[0]), fv = sigf(g4[1]);
    float gg = tanh_f(g4[2]), ov = sigf(g4[3]);
    float c = fv*cst + iv*gg;
    cst = c;
    float h = ov * tanh_f(c);
    hcat[(size_t)(s*64 + bb + cb)*512 + dir*256 + cj] = f2bf(h);
    int q = (int)rintf(h * 127.f);
    Hs[(t + 1) & 1][cb*256 + (cj ^ (cb << 4))] = (s8)q;
    gp = gq;
    #pragma unroll
    for (int g = 0; g < 4; g++) gcur[g] = gnxt[g];
    bar_l();
  }
}

// ---------------- K4: P = Hcat @ fc_w^T + fc_b + lm*wfc  [32768 x 16] fp32 ----------------
__global__ __launch_bounds__(256) void k4_fc(
    const u16* __restrict__ hcat, const float* __restrict__ fcw, const float* __restrict__ fcb,
    const float* __restrict__ lmp, const float* __restrict__ wfc, float* __restrict__ Pout)
{
  const int wv = threadIdx.x >> 6, lane = threadIdx.x & 63;
  const int lr = lane & 15, lq = lane >> 4;
  const int mt = blockIdx.x*4 + wv;
  short8 bfr[16];
  #pragma unroll
  for (int kk = 0; kk < 16; kk++){
    const float* wr = fcw + (size_t)lr*512 + kk*32 + lq*8;
    f32x4 w0 = *(const f32x4*)wr;
    f32x4 w1 = *(const f32x4*)(wr + 4);
    short8 sv;
    #pragma unroll
    for (int e = 0; e < 4; e++){ sv[e] = (short)f2bf(w0[e]); sv[4+e] = (short)f2bf(w1[e]); }
    bfr[kk] = sv;
  }
  f32x4 acc = (f32x4){0.f,0.f,0.f,0.f};
  #pragma unroll
  for (int kk = 0; kk < 16; kk++){
    short8 af = *(const short8*)(hcat + (size_t)(mt*16 + lr)*512 + kk*32 + lq*8);
    acc = __builtin_amdgcn_mfma_f32_16x16x32_bf16(af, bfr[kk], acc, 0,0,0);
  }
  const int cur = lr;
  float fb = fcb[cur];
  float wf = wfc[cur];
  #pragma unroll
  for (int r = 0; r < 4; r++){
    int m = mt*16 + lq*4 + r;
    int b = m & 63, s = m >> 6;
    float lmv = lmp[b*512 + s];
    Pout[(size_t)m*16 + cur] = acc[r] + fb + lmv*wf;
  }
}

// ---------------- K5: Viterbi (one wave per batch element, prefetched) ----------------
__global__ __launch_bounds__(64) void k5_vit(
    const float* __restrict__ Pg, const float* __restrict__ Am,
    float* __restrict__ dout, float* __restrict__ dl, u8* __restrict__ psi)
{
  const int b = blockIdx.x, lane = threadIdx.x;
  const int cur = lane >> 2, q = lane & 3;
  float Ar[4];
  #pragma unroll
  for (int r = 0; r < 4; r++) Ar[r] = Am[(4*q + r)*16 + cur];
  float val = Pg[(size_t)b*16 + cur];
  if (q == 0) dl[(size_t)b*16 + cur] = val;
  float xr[4];
  #pragma unroll
  for (int i = 0; i < 4; i++) xr[i] = Pg[(size_t)((1+i)*64 + b)*16 + cur];
  for (int s = 1; s < 512; s++){
    float x = xr[(s-1)&3];
    if (s + 4 < 512) xr[(s-1)&3] = Pg[(size_t)((s+4)*64 + b)*16 + cur];
    float best = -3.0e38f; int bi = 0;
    #pragma unroll
    for (int r = 0; r < 4; r++){
      float dp = __shfl(val, (4*q + r)*4, 64);
      float sc = (dp + Ar[r]) + x;
      if (sc > best){ best = sc; bi = 4*q + r; }
    }
    #pragma unroll
    for (int m = 1; m <= 2; m <<= 1){
      float ov = __shfl_xor(best, m, 64);
      int   oi = __shfl_xor(bi, m, 64);
      if (ov > best || (ov == best && oi < bi)){ best = ov; bi = oi; }
    }
    val = best;
    if (q == 0){
      dl[(size_t)(s*64 + b)*16 + cur] = best;
      psi[(size_t)(s*64 + b)*16 + cur] = (u8)bi;
    }
  }
  __syncthreads();
  float bv = val; int bix = cur;
  #pragma unroll
  for (int m = 1; m < 64; m <<= 1){
    float ov = __shfl_xor(bv, m, 64);
    int   oi = __shfl_xor(bix, m, 64);
    if (ov > bv || (ov == bv && oi < bix)){ bv = ov; bix = oi; }
  }
  int tag = bix;
  float score = bv;
  if (lane == 0) dout[b*512 + 511] = (float)tag;
  int pvr[4]; float dvr[4];
  #pragma unroll
  for (int i = 0; i < 4; i++){
    if (lane < 16){
      pvr[i] = psi[(size_t)((511-i)*64 + b)*16 + lane];
      dvr[i] = dl[(size_t)((510-i)*64 + b)*16 + lane];
    }
  }
  for (int t = 510; t >= 0; t--){
    const int slot = (510 - t) & 3;
    int pv = pvr[slot]; float dv = dvr[slot];
    if (t >= 4 && lane < 16){
      pvr[slot] = psi[(size_t)((t-3)*64 + b)*16 + lane];
      dvr[slot] = dl[(size_t)((t-4)*64 + b)*16 + lane];
    }
    int prev = __shfl(pv, tag, 64);
    score += __shfl(dv, prev, 64);
    if (lane == 0) dout[b*512 + t] = (float)prev;
    tag = prev;
  }
  if (lane == 0) dout[32768 + b] = score;
}

// ---------------- launcher ----------------
extern "C" void kernel_launch(void* const* d_in, const int* in_sizes, int n_in,
                              void* d_out, int out_size, void* d_ws, size_t ws_size,
                              hipStream_t stream)
{
  (void)in_sizes; (void)n_in; (void)out_size;
  if (ws_size < REQUIRED) return;

  const int*   X    = (const int*)d_in[0];
  const float* lm   = (const float*)d_in[1];
  const int*   tg   = (const int*)d_in[2];
  const int*   ch   = (const int*)d_in[3];
  const float* etab = (const float*)d_in[4];
  const float* ttab = (const float*)d_in[5];
  const float* ctab = (const float*)d_in[6];
  const float* cw   = (const float*)d_in[7];
  const float* cb   = (const float*)d_in[8];
  const float* wihf = (const float*)d_in[9];
  const float* whhf = (const float*)d_in[10];
  const float* bihf = (const float*)d_in[11];
  const float* bhhf = (const float*)d_in[12];
  const float* wihb = (const float*)d_in[13];
  const float* whhb = (const float*)d_in[14];
  const float* bihb = (const float*)d_in[15];
  const float* bhhb = (const float*)d_in[16];
  const float* fcw  = (const float*)d_in[17];
  const float* fcb  = (const float*)d_in[18];
  const float* Am   = (const float*)d_in[19];
  const float* wdp  = (const float*)d_in[20];

  char* ws = (char*)d_ws;
  u16*   gi   = (u16*)(ws + OFF_GI);
  u16*   feat = (u16*)(ws + OFF_B);
  u16*   hcat = (u16*)(ws + OFF_B);
  u16*   wih  = (u16*)(ws + OFF_WIH);
  s8*    wq   = (s8*)(ws + OFF_WQ);
  float* sc2  = (float*)(ws + OFF_SC);
  float* Pg   = (float*)(ws + OFF_P);
  float* dlt  = (float*)(ws + OFF_DL);
  u8*    psi  = (u8*)(ws + OFF_PSI);
  float* bias = (float*)(ws + OFF_BIAS);
  float* wfc  = (float*)(ws + OFF_WFC);
  float* dout = (float*)d_out;

  k0_pack<<<2048, 256, 0, stream>>>(wihf, wihb, wih);
  k0q<<<512, 256, 0, stream>>>(whhf, whhb, wq, sc2);
  k0_misc<<<1, 256, 0, stream>>>(bihf, bhhf, bihb, bhhb, fcw, wdp, bias, wfc);
  k1_feat<<<dim3(128, 64), 256, 0, stream>>>(X, tg, ch, etab, ttab, ctab, cw, cb, feat);
  k2_gemm<<<dim3(256, 16), 256, 0, stream>>>(feat, wih, bias, gi);
  k3_lstm<<<64, 512, 0, stream>>>(wq, sc2, gi, hcat);
  k4_fc<<<512, 256, 0, stream>>>(hcat, fcw, fcb, lm, wfc, Pg);
  k5_vit<<<64, 64, 0, stream>>>(Pg, Am, dout, dlt, psi);
}

// Round 7
// 1290.054 us; speedup vs baseline: 2.4547x; 1.0734x over previous
//
#include <hip/hip_runtime.h>

// BiLSTM-CRF on MI355X. Round 7: K3 holds ALL W_hh i8 fragments in VGPRs
// (no in-loop LDS weight reads; LDS 16KB), 2-step gi prefetch; K2 grid
// swapped n-fastest for L2 A-panel reuse.

#define DEV __device__ __forceinline__
typedef unsigned short u16;
typedef unsigned int   u32;
typedef unsigned char  u8;
typedef signed char    s8;
using short8  = __attribute__((ext_vector_type(8))) short;
using f32x4   = __attribute__((ext_vector_type(4))) float;
using int4v   = __attribute__((ext_vector_type(4))) int;

DEV float bf2f(u16 u){ union{u32 i; float f;} v; v.i = ((u32)u)<<16; return v.f; }
DEV u16 f2bf(float f){ u32 x = __float_as_uint(f); return (u16)((x + 0x7fffu + ((x>>16)&1u)) >> 16); }
DEV float sigf(float x){ return __builtin_amdgcn_rcpf(1.f + __expf(-x)); }
DEV float tanh_f(float x){ return 1.f - 2.f*__builtin_amdgcn_rcpf(__expf(2.f*x) + 1.f); }

typedef __attribute__((address_space(1))) const u32 GU;
typedef __attribute__((address_space(3))) u32 LU;
DEV void gld_lds16(const void* g, void* l){
  __builtin_amdgcn_global_load_lds((GU*)g, (LU*)l, 16, 0, 0);
}
// LDS-only barrier: no vmcnt drain (global stores/prefetch float across)
DEV void bar_l(){
  __builtin_amdgcn_sched_barrier(0);
  asm volatile("s_waitcnt lgkmcnt(0)" ::: "memory");
  __builtin_amdgcn_s_barrier();
  __builtin_amdgcn_sched_barrier(0);
}

// ---------------- ws layout (aliased; total ~170MB) ----------------
static const size_t OFF_GI   = 0;
static const size_t OFF_P    = 0;
static const size_t OFF_DL   = OFF_P  + (size_t)32768*16*4;
static const size_t OFF_PSI  = OFF_DL + (size_t)32768*16*4;
static const size_t OFF_B    = (size_t)134217728;
static const size_t OFF_WIH  = OFF_B    + (size_t)33554432;
static const size_t OFF_WQ   = OFF_WIH  + (size_t)1703936;   // 512KB i8 frags
static const size_t OFF_SC   = OFF_WQ   + (size_t)524288;    // 8KB scales
static const size_t OFF_BIAS = OFF_SC   + 8192;
static const size_t OFF_WFC  = OFF_BIAS + 8192;
static const size_t REQUIRED = OFF_WFC  + 256;

// ---------------- K0: pack W_ih (f32 -> bf16 [2048][416]) ----------------
__global__ void k0_pack(const float* __restrict__ wihf, const float* __restrict__ wihb,
                        u16* __restrict__ wih)
{
  int n = blockIdx.x, tid = threadIdx.x;
  const float* src = (n < 1024) ? (wihf + (size_t)n*400) : (wihb + (size_t)(n-1024)*400);
  u32* dst = (u32*)(wih + (size_t)n*416);
  if (tid < 208){
    int j = tid*2;
    u32 v = 0u;
    if (j < 400){
      float2 f = *(const float2*)(src + j);
      v = (u32)f2bf(f.x) | ((u32)f2bf(f.y) << 16);
    }
    dst[tid] = v;
  }
}

// ---------------- K0q: quantize W_hh rows to i8 MFMA fragments ----------------
__global__ __launch_bounds__(256) void k0q(
    const float* __restrict__ whhf, const float* __restrict__ whhb,
    s8* __restrict__ wq, float* __restrict__ sc2)
{
  const int row = blockIdx.x*4 + (threadIdx.x >> 6);
  const int lane = threadIdx.x & 63;
  const float* src = (row < 1024) ? (whhf + (size_t)row*256)
                                  : (whhb + (size_t)(row-1024)*256);
  f32x4 v = *(const f32x4*)(src + lane*4);
  float m = fmaxf(fmaxf(fabsf(v[0]), fabsf(v[1])), fmaxf(fabsf(v[2]), fabsf(v[3])));
  #pragma unroll
  for (int d = 1; d < 64; d <<= 1) m = fmaxf(m, __shfl_xor(m, d, 64));
  float inv = 127.f / (m + 1e-30f);
  u32 pack = 0;
  #pragma unroll
  for (int e = 0; e < 4; e++){
    int q = (int)rintf(v[e]*inv);
    q = q > 127 ? 127 : (q < -127 ? -127 : q);
    pack |= ((u32)(u8)(s8)q) << (8*e);
  }
  const int dir = row >> 10, n = row & 1023;
  const int g = n >> 8, j = n & 255, w2 = j >> 4, lr2 = j & 15;
  const int kk = lane >> 4, lq2 = (lane >> 2) & 3, e4 = lane & 3;
  u32* wq32 = (u32*)wq;
  wq32[dir*65536 + (((g*16 + w2)*4 + kk)*64 + lq2*16 + lr2)*4 + e4] = pack;
  if (lane == 0) sc2[row] = m * (1.f/16129.f);
}

// ---------------- K0b: bias sums (fp32) + wfc = fc_w @ wd (parallel) ----------------
__global__ void k0_misc(const float* bihf, const float* bhhf, const float* bihb, const float* bhhb,
                        const float* fcw, const float* wdp, float* bias, float* wfc)
{
  __shared__ float red[256];
  int tid = threadIdx.x;
  for (int n = tid; n < 2048; n += 256){
    bias[n] = (n < 1024) ? (bihf[n] + bhhf[n]) : (bihb[n-1024] + bhhb[n-1024]);
  }
  const int cur = tid & 15, part = tid >> 4;
  float s = 0.f;
  for (int k = part*32; k < part*32 + 32; k++) s += fcw[cur*512 + k] * wdp[k];
  red[tid] = s;
  __syncthreads();
  if (tid < 16){
    float t = 0.f;
    #pragma unroll
    for (int p = 0; p < 16; p++) t += red[p*16 + tid];
    wfc[tid] = t;
  }
}

// ---------------- K1: features -> feat[s*64+b][416] bf16 ----------------
__global__ __launch_bounds__(256) void k1_feat(
    const int* __restrict__ X, const int* __restrict__ tg, const int* __restrict__ ch,
    const float* __restrict__ etab, const float* __restrict__ ttab, const float* __restrict__ ctab,
    const float* __restrict__ cw, const float* __restrict__ cb, u16* __restrict__ feat)
{
  const int sb = blockIdx.x, b = blockIdx.y, tid = threadIdx.x;
  __shared__ float ce_s[66*60];
  __shared__ float w_s[150*52];
  for (int i = tid; i < 600; i += 256){
    int wl = i/150, j = i - wl*150;
    int s = sb*4 + wl;
    int idx = X[b*512 + s];
    float2 f = *(const float2*)(etab + (size_t)idx*300 + j*2);
    *(u32*)(feat + (size_t)(s*64 + b)*416 + j*2) = (u32)f2bf(f.x) | ((u32)f2bf(f.y) << 16);
  }
  for (int i = tid; i < 100; i += 256){
    int wl = i/25, j = i - wl*25;
    int s = sb*4 + wl;
    int idx = tg[b*512 + s];
    float2 f = *(const float2*)(ttab + (size_t)idx*50 + j*2);
    *(u32*)(feat + (size_t)(s*64 + b)*416 + 300 + j*2) = (u32)f2bf(f.x) | ((u32)f2bf(f.y) << 16);
  }
  if (tid < 32){
    int wl = tid>>3, j = tid&7;
    int s = sb*4 + wl;
    *(u32*)(feat + (size_t)(s*64 + b)*416 + 400 + j*2) = 0u;
  }
  for (int i = tid; i < 3300; i += 256){
    int qq = i/50, ce = i - qq*50;
    int p = sb*64 - 1 + qq;
    float v = 0.f;
    if (p >= 0 && p < 8192){
      int ci = ch[b*8192 + p];
      v = ctab[ci*50 + ce];
    }
    ce_s[qq*60 + ce] = v;
  }
  for (int i = tid; i < 7500; i += 256){
    int cc = i/150, r2 = i - cc*150;
    int ce = r2/3, dc = r2 - ce*3;
    w_s[(cc*3 + dc)*52 + ce] = cw[i];
  }
  __syncthreads();
  const int li = tid & 15, jg = tid >> 4;
  float acc[4][3];
  #pragma unroll
  for (int k=0;k<4;k++){ acc[k][0]=0.f; acc[k][1]=0.f; acc[k][2]=0.f; }
  #pragma unroll
  for (int dc = 0; dc < 3; dc++){
    for (int ceb = 0; ceb < 48; ceb += 4){
      f32x4 w0 = *(const f32x4*)&w_s[((3*jg+0)*3 + dc)*52 + ceb];
      f32x4 w1 = *(const f32x4*)&w_s[((3*jg+1)*3 + dc)*52 + ceb];
      f32x4 w2 = *(const f32x4*)&w_s[((3*jg+2)*3 + dc)*52 + ceb];
      #pragma unroll
      for (int k = 0; k < 4; k++){
        f32x4 cv = *(const f32x4*)&ce_s[(16*k + li + dc)*60 + ceb];
        #pragma unroll
        for (int e = 0; e < 4; e++){
          acc[k][0] += cv[e]*w0[e];
          acc[k][1] += cv[e]*w1[e];
          acc[k][2] += cv[e]*w2[e];
        }
      }
    }
    float w0a = w_s[((3*jg+0)*3+dc)*52 + 48], w0b = w_s[((3*jg+0)*3+dc)*52 + 49];
    float w1a = w_s[((3*jg+1)*3+dc)*52 + 48], w1b = w_s[((3*jg+1)*3+dc)*52 + 49];
    float w2a = w_s[((3*jg+2)*3+dc)*52 + 48], w2b = w_s[((3*jg+2)*3+dc)*52 + 49];
    #pragma unroll
    for (int k = 0; k < 4; k++){
      float ca = ce_s[(16*k + li + dc)*60 + 48];
      float cb2 = ce_s[(16*k + li + dc)*60 + 49];
      acc[k][0] += ca*w0a + cb2*w0b;
      acc[k][1] += ca*w1a + cb2*w1b;
      acc[k][2] += ca*w2a + cb2*w2b;
    }
  }
  #pragma unroll
  for (int m = 1; m < 16; m <<= 1)
    #pragma unroll
    for (int k=0;k<4;k++)
      #pragma unroll
      for (int c=0;c<3;c++)
        acc[k][c] = fmaxf(acc[k][c], __shfl_xor(acc[k][c], m, 64));
  if (li == 0){
    #pragma unroll
    for (int k=0;k<4;k++)
      #pragma unroll
      for (int c=0;c<3;c++){
        int cc = 3*jg + c;
        int s = sb*4 + k;
        feat[(size_t)(s*64 + b)*416 + 350 + cc] = f2bf(acc[k][c] + cb[cc]);
      }
  }
  if (tid < 128){
    int pl = tid & 63, cc = 48 + (tid >> 6);
    float a2 = 0.f;
    #pragma unroll
    for (int dc = 0; dc < 3; dc++){
      for (int ceb = 0; ceb < 48; ceb += 4){
        f32x4 wv = *(const f32x4*)&w_s[(cc*3 + dc)*52 + ceb];
        f32x4 cv = *(const f32x4*)&ce_s[(pl + dc)*60 + ceb];
        a2 += cv[0]*wv[0] + cv[1]*wv[1] + cv[2]*wv[2] + cv[3]*wv[3];
      }
      a2 += ce_s[(pl+dc)*60 + 48]*w_s[(cc*3+dc)*52 + 48]
          + ce_s[(pl+dc)*60 + 49]*w_s[(cc*3+dc)*52 + 49];
    }
    #pragma unroll
    for (int m = 1; m < 16; m <<= 1) a2 = fmaxf(a2, __shfl_xor(a2, m, 64));
    if ((tid & 15) == 0){
      int s = sb*4 + ((tid & 63) >> 4);
      feat[(size_t)(s*64 + b)*416 + 350 + cc] = f2bf(a2 + cb[cc]);
    }
  }
}

// ---------------- K2: gi = bf16(feat @ wih^T + bias)  [32768 x 2048] ----------------
// grid: x = n-block (16), y = m-block (256); n fastest for L2 A-panel reuse.
__global__ __launch_bounds__(256) void k2_gemm(
    const u16* __restrict__ featp, const u16* __restrict__ wihp,
    const float* __restrict__ bias, u16* __restrict__ gi)
{
  const int m0 = blockIdx.y*128, n0 = blockIdx.x*128;
  const int tid = threadIdx.x, wv = tid>>6, lane = tid&63;
  const int lr = lane & 15, lq = lane >> 4;
  const int wm = (wv>>1)*64, wn = (wv&1)*64;
  __shared__ u16 As[4096], Bs[4096];
  f32x4 acc[4][4];
  #pragma unroll
  for (int a=0;a<4;a++)
    #pragma unroll
    for (int c=0;c<4;c++) acc[a][c] = (f32x4){0.f,0.f,0.f,0.f};
  for (int k0 = 0; k0 < 416; k0 += 32){
    __syncthreads();
    #pragma unroll
    for (int i = 0; i < 2; i++){
      int c = i*4 + wv;
      gld_lds16(featp + (size_t)(m0 + c*16 + (lane>>2))*416 + k0 + (lane&3)*8, &As[c*512]);
      gld_lds16(wihp  + (size_t)(n0 + c*16 + (lane>>2))*416 + k0 + (lane&3)*8, &Bs[c*512]);
    }
    __syncthreads();
    short8 af[4], bfr[4];
    #pragma unroll
    for (int mt=0; mt<4; mt++) af[mt]  = *(const short8*)(As + (wm + mt*16 + lr)*32 + lq*8);
    #pragma unroll
    for (int nt=0; nt<4; nt++) bfr[nt] = *(const short8*)(Bs + (wn + nt*16 + lr)*32 + lq*8);
    #pragma unroll
    for (int mt=0; mt<4; mt++)
      #pragma unroll
      for (int nt=0; nt<4; nt++)
        acc[mt][nt] = __builtin_amdgcn_mfma_f32_16x16x32_bf16(af[mt], bfr[nt], acc[mt][nt], 0,0,0);
  }
  #pragma unroll
  for (int nt=0; nt<4; nt++){
    float bv = bias[n0 + wn + nt*16 + lr];
    #pragma unroll
    for (int mt=0; mt<4; mt++)
      #pragma unroll
      for (int r=0; r<4; r++)
        gi[(size_t)(m0 + wm + mt*16 + lq*4 + r)*2048 + n0 + wn + nt*16 + lr]
            = f2bf(acc[mt][nt][r] + bv);
  }
}

// ---------------- K3: recurrent BiLSTM, 64 blocks x 512 thr, all-VGPR weights ----------------
// dir = blk>>5, batch rows bb = (blk&31)*2. 8 waves; wave w owns j-slices 2w,2w+1.
// W_hh i8: ALL 4 kk in VGPR (128 regs). h dbuf LDS (8KB) + xbuf (8KB). 2-step gi prefetch.
__global__ __launch_bounds__(512, 2) void k3_lstm(
    const s8* __restrict__ wq, const float* __restrict__ sc2,
    const u16* __restrict__ gi, u16* __restrict__ hcat)
{
  const int dir = blockIdx.x >> 5;
  const int bb  = (blockIdx.x & 31) * 2;
  const int tid = threadIdx.x;
  const int w = tid >> 6, lane = tid & 63;
  const int lr = lane & 15, lq = lane >> 4;
  const int cb = tid >> 8, cj = tid & 255;   // cell identity (batch row, hidden j)

  __shared__ s8 Hs[2][4096];     // h dbuf [16 rows (2 valid)][256], col^=(b<<4)
  __shared__ float xbuf[2048];   // [2][256][4] pre-activation exchange

  const s8* wqd = wq + dir*262144;
  // ALL weight fragments in VGPRs: 2 slices x 4 gates x 4 kk
  int4v bq[2][4][4];
  #pragma unroll
  for (int sl = 0; sl < 2; sl++)
    #pragma unroll
    for (int g = 0; g < 4; g++)
      #pragma unroll
      for (int kk = 0; kk < 4; kk++)
        bq[sl][g][kk] = *(const int4v*)(wqd + (((((g*16 + 2*w + sl)*4 + kk)*64) + lane) << 4));

  float scl[4];
  #pragma unroll
  for (int g = 0; g < 4; g++) scl[g] = sc2[dir*1024 + g*256 + cj];

  // zero both h buffers (rows 2..15 stay zero forever)
  *(uint2*)&Hs[0][tid*8] = (uint2){0u,0u};
  *(uint2*)&Hs[1][tid*8] = (uint2){0u,0u};

  float cst = 0.f;
  const ptrdiff_t dstep = dir ? -(ptrdiff_t)131072 : (ptrdiff_t)131072;  // +-64*2048
  const u16* g0 = gi + (size_t)((dir ? 511 : 0)*64 + bb + cb)*2048 + dir*1024 + cj;
  u32 gcur[4], gn1[4], gn2[4];
  #pragma unroll
  for (int g = 0; g < 4; g++) gcur[g] = g0[g*256];
  const u16* g1 = g0 + dstep;
  #pragma unroll
  for (int g = 0; g < 4; g++) gn1[g] = g1[g*256];
  const u16* gpref = g1;
  __syncthreads();

  #pragma unroll 1
  for (int t = 0; t < 512; t++){
    const int s = dir ? (511 - t) : t;
    // prefetch step t+2's gate inputs (2 steps ahead)
    if (t + 2 < 512) gpref += dstep;
    #pragma unroll
    for (int g = 0; g < 4; g++) gn2[g] = gpref[g*256];
    // MFMA phase (weights all in VGPR)
    const s8* hb = Hs[t & 1];
    int4v aq[4];
    #pragma unroll
    for (int kk = 0; kk < 4; kk++)
      aq[kk] = *(const int4v*)(hb + lr*256 + ((kk*64 + lq*16) ^ (lr << 4)));
    int4v acc[2][4];
    #pragma unroll
    for (int sl = 0; sl < 2; sl++)
      #pragma unroll
      for (int g = 0; g < 4; g++) acc[sl][g] = (int4v){0,0,0,0};
    #pragma unroll
    for (int kk = 0; kk < 4; kk++)
      #pragma unroll
      for (int sl = 0; sl < 2; sl++)
        #pragma unroll
        for (int g = 0; g < 4; g++)
          acc[sl][g] = __builtin_amdgcn_mfma_i32_16x16x64_i8(aq[kk], bq[sl][g][kk], acc[sl][g], 0,0,0);
    // redistribute: valid rows r=0,1 (lq==0 lanes) -> xbuf[r][j][g]
    if (lq == 0){
      #pragma unroll
      for (int sl = 0; sl < 2; sl++){
        const int j = (2*w + sl)*16 + lr;
        #pragma unroll
        for (int r = 0; r < 2; r++){
          f32x4 v = (f32x4){(float)acc[sl][0][r], (float)acc[sl][1][r],
                            (float)acc[sl][2][r], (float)acc[sl][3][r]};
          *(f32x4*)&xbuf[(r*256 + j)*4] = v;
        }
      }
    }
    bar_l();
    // cell update: 1 cell per thread (cb, cj); xbuf index (cb*256+cj) == tid
    f32x4 p = *(const f32x4*)&xbuf[tid*4];
    float g4[4];
    #pragma unroll
    for (int g = 0; g < 4; g++) g4[g] = bf2f((u16)gcur[g]) + p[g]*scl[g];
    float iv = sigf(g4[0]), fv = sigf(g4[1]);
    float gg = tanh_f(g4[2]), ov = sigf(g4[3]);
    float c = fv*cst + iv*gg;
    cst = c;
    float h = ov * tanh_f(c);
    hcat[(size_t)(s*64 + bb + cb)*512 + dir*256 + cj] = f2bf(h);
    int q = (int)rintf(h * 127.f);
    Hs[(t + 1) & 1][cb*256 + (cj ^ (cb << 4))] = (s8)q;
    #pragma unroll
    for (int g = 0; g < 4; g++){ gcur[g] = gn1[g]; gn1[g] = gn2[g]; }
    bar_l();
  }
}

// ---------------- K4: P = Hcat @ fc_w^T + fc_b + lm*wfc  [32768 x 16] fp32 ----------------
__global__ __launch_bounds__(256) void k4_fc(
    const u16* __restrict__ hcat, const float* __restrict__ fcw, const float* __restrict__ fcb,
    const float* __restrict__ lmp, const float* __restrict__ wfc, float* __restrict__ Pout)
{
  const int wv = threadIdx.x >> 6, lane = threadIdx.x & 63;
  const int lr = lane & 15, lq = lane >> 4;
  const int mt = blockIdx.x*4 + wv;
  short8 bfr[16];
  #pragma unroll
  for (int kk = 0; kk < 16; kk++){
    const float* wr = fcw + (size_t)lr*512 + kk*32 + lq*8;
    f32x4 w0 = *(const f32x4*)wr;
    f32x4 w1 = *(const f32x4*)(wr + 4);
    short8 sv;
    #pragma unroll
    for (int e = 0; e < 4; e++){ sv[e] = (short)f2bf(w0[e]); sv[4+e] = (short)f2bf(w1[e]); }
    bfr[kk] = sv;
  }
  f32x4 acc = (f32x4){0.f,0.f,0.f,0.f};
  #pragma unroll
  for (int kk = 0; kk < 16; kk++){
    short8 af = *(const short8*)(hcat + (size_t)(mt*16 + lr)*512 + kk*32 + lq*8);
    acc = __builtin_amdgcn_mfma_f32_16x16x32_bf16(af, bfr[kk], acc, 0,0,0);
  }
  const int cur = lr;
  float fb = fcb[cur];
  float wf = wfc[cur];
  #pragma unroll
  for (int r = 0; r < 4; r++){
    int m = mt*16 + lq*4 + r;
    int b = m & 63, s = m >> 6;
    float lmv = lmp[b*512 + s];
    Pout[(size_t)m*16 + cur] = acc[r] + fb + lmv*wf;
  }
}

// ---------------- K5: Viterbi (one wave per batch element, prefetched) ----------------
__global__ __launch_bounds__(64) void k5_vit(
    const float* __restrict__ Pg, const float* __restrict__ Am,
    float* __restrict__ dout, float* __restrict__ dl, u8* __restrict__ psi)
{
  const int b = blockIdx.x, lane = threadIdx.x;
  const int cur = lane >> 2, q = lane & 3;
  float Ar[4];
  #pragma unroll
  for (int r = 0; r < 4; r++) Ar[r] = Am[(4*q + r)*16 + cur];
  float val = Pg[(size_t)b*16 + cur];
  if (q == 0) dl[(size_t)b*16 + cur] = val;
  float xr[4];
  #pragma unroll
  for (int i = 0; i < 4; i++) xr[i] = Pg[(size_t)((1+i)*64 + b)*16 + cur];
  for (int s = 1; s < 512; s++){
    float x = xr[(s-1)&3];
    if (s + 4 < 512) xr[(s-1)&3] = Pg[(size_t)((s+4)*64 + b)*16 + cur];
    float best = -3.0e38f; int bi = 0;
    #pragma unroll
    for (int r = 0; r < 4; r++){
      float dp = __shfl(val, (4*q + r)*4, 64);
      float sc = (dp + Ar[r]) + x;
      if (sc > best){ best = sc; bi = 4*q + r; }
    }
    #pragma unroll
    for (int m = 1; m <= 2; m <<= 1){
      float ov = __shfl_xor(best, m, 64);
      int   oi = __shfl_xor(bi, m, 64);
      if (ov > best || (ov == best && oi < bi)){ best = ov; bi = oi; }
    }
    val = best;
    if (q == 0){
      dl[(size_t)(s*64 + b)*16 + cur] = best;
      psi[(size_t)(s*64 + b)*16 + cur] = (u8)bi;
    }
  }
  __syncthreads();
  float bv = val; int bix = cur;
  #pragma unroll
  for (int m = 1; m < 64; m <<= 1){
    float ov = __shfl_xor(bv, m, 64);
    int   oi = __shfl_xor(bix, m, 64);
    if (ov > bv || (ov == bv && oi < bix)){ bv = ov; bix = oi; }
  }
  int tag = bix;
  float score = bv;
  if (lane == 0) dout[b*512 + 511] = (float)tag;
  int pvr[4]; float dvr[4];
  #pragma unroll
  for (int i = 0; i < 4; i++){
    if (lane < 16){
      pvr[i] = psi[(size_t)((511-i)*64 + b)*16 + lane];
      dvr[i] = dl[(size_t)((510-i)*64 + b)*16 + lane];
    }
  }
  for (int t = 510; t >= 0; t--){
    const int slot = (510 - t) & 3;
    int pv = pvr[slot]; float dv = dvr[slot];
    if (t >= 4 && lane < 16){
      pvr[slot] = psi[(size_t)((t-3)*64 + b)*16 + lane];
      dvr[slot] = dl[(size_t)((t-4)*64 + b)*16 + lane];
    }
    int prev = __shfl(pv, tag, 64);
    score += __shfl(dv, prev, 64);
    if (lane == 0) dout[b*512 + t] = (float)prev;
    tag = prev;
  }
  if (lane == 0) dout[32768 + b] = score;
}

// ---------------- launcher ----------------
extern "C" void kernel_launch(void* const* d_in, const int* in_sizes, int n_in,
                              void* d_out, int out_size, void* d_ws, size_t ws_size,
                              hipStream_t stream)
{
  (void)in_sizes; (void)n_in; (void)out_size;
  if (ws_size < REQUIRED) return;

  const int*   X    = (const int*)d_in[0];
  const float* lm   = (const float*)d_in[1];
  const int*   tg   = (const int*)d_in[2];
  const int*   ch   = (const int*)d_in[3];
  const float* etab = (const float*)d_in[4];
  const float* ttab = (const float*)d_in[5];
  const float* ctab = (const float*)d_in[6];
  const float* cw   = (const float*)d_in[7];
  const float* cb   = (const float*)d_in[8];
  const float* wihf = (const float*)d_in[9];
  const float* whhf = (const float*)d_in[10];
  const float* bihf = (const float*)d_in[11];
  const float* bhhf = (const float*)d_in[12];
  const float* wihb = (const float*)d_in[13];
  const float* whhb = (const float*)d_in[14];
  const float* bihb = (const float*)d_in[15];
  const float* bhhb = (const float*)d_in[16];
  const float* fcw  = (const float*)d_in[17];
  const float* fcb  = (const float*)d_in[18];
  const float* Am   = (const float*)d_in[19];
  const float* wdp  = (const float*)d_in[20];

  char* ws = (char*)d_ws;
  u16*   gi   = (u16*)(ws + OFF_GI);
  u16*   feat = (u16*)(ws + OFF_B);
  u16*   hcat = (u16*)(ws + OFF_B);
  u16*   wih  = (u16*)(ws + OFF_WIH);
  s8*    wq   = (s8*)(ws + OFF_WQ);
  float* sc2  = (float*)(ws + OFF_SC);
  float* Pg   = (float*)(ws + OFF_P);
  float* dlt  = (float*)(ws + OFF_DL);
  u8*    psi  = (u8*)(ws + OFF_PSI);
  float* bias = (float*)(ws + OFF_BIAS);
  float* wfc  = (float*)(ws + OFF_WFC);
  float* dout = (float*)d_out;

  k0_pack<<<2048, 256, 0, stream>>>(wihf, wihb, wih);
  k0q<<<512, 256, 0, stream>>>(whhf, whhb, wq, sc2);
  k0_misc<<<1, 256, 0, stream>>>(bihf, bhhf, bihb, bhhb, fcw, wdp, bias, wfc);
  k1_feat<<<dim3(128, 64), 256, 0, stream>>>(X, tg, ch, etab, ttab, ctab, cw, cb, feat);
  k2_gemm<<<dim3(16, 256), 256, 0, stream>>>(feat, wih, bias, gi);
  k3_lstm<<<64, 512, 0, stream>>>(wq, sc2, gi, hcat);
  k4_fc<<<512, 256, 0, stream>>>(hcat, fcw, fcb, lm, wfc, Pg);
  k5_vit<<<64, 64, 0, stream>>>(Pg, Am, dout, dlt, psi);
}

// Round 8
// 1172.834 us; speedup vs baseline: 2.7000x; 1.0999x over previous
//
#include <hip/hip_runtime.h>

// BiLSTM-CRF on MI355X. Round 8: K5 Viterbi de-scratched (rule #20): ring
// buffers replaced by named registers via 4x unroll in both scan and backtrace.
// K0-K4 unchanged from round 7.

#define DEV __device__ __forceinline__
typedef unsigned short u16;
typedef unsigned int   u32;
typedef unsigned char  u8;
typedef signed char    s8;
using short8  = __attribute__((ext_vector_type(8))) short;
using f32x4   = __attribute__((ext_vector_type(4))) float;
using int4v   = __attribute__((ext_vector_type(4))) int;

DEV float bf2f(u16 u){ union{u32 i; float f;} v; v.i = ((u32)u)<<16; return v.f; }
DEV u16 f2bf(float f){ u32 x = __float_as_uint(f); return (u16)((x + 0x7fffu + ((x>>16)&1u)) >> 16); }
DEV float sigf(float x){ return __builtin_amdgcn_rcpf(1.f + __expf(-x)); }
DEV float tanh_f(float x){ return 1.f - 2.f*__builtin_amdgcn_rcpf(__expf(2.f*x) + 1.f); }

typedef __attribute__((address_space(1))) const u32 GU;
typedef __attribute__((address_space(3))) u32 LU;
DEV void gld_lds16(const void* g, void* l){
  __builtin_amdgcn_global_load_lds((GU*)g, (LU*)l, 16, 0, 0);
}
// LDS-only barrier: no vmcnt drain (global stores/prefetch float across)
DEV void bar_l(){
  __builtin_amdgcn_sched_barrier(0);
  asm volatile("s_waitcnt lgkmcnt(0)" ::: "memory");
  __builtin_amdgcn_s_barrier();
  __builtin_amdgcn_sched_barrier(0);
}

// ---------------- ws layout (aliased; total ~170MB) ----------------
static const size_t OFF_GI   = 0;
static const size_t OFF_P    = 0;
static const size_t OFF_DL   = OFF_P  + (size_t)32768*16*4;
static const size_t OFF_PSI  = OFF_DL + (size_t)32768*16*4;
static const size_t OFF_B    = (size_t)134217728;
static const size_t OFF_WIH  = OFF_B    + (size_t)33554432;
static const size_t OFF_WQ   = OFF_WIH  + (size_t)1703936;   // 512KB i8 frags
static const size_t OFF_SC   = OFF_WQ   + (size_t)524288;    // 8KB scales
static const size_t OFF_BIAS = OFF_SC   + 8192;
static const size_t OFF_WFC  = OFF_BIAS + 8192;
static const size_t REQUIRED = OFF_WFC  + 256;

// ---------------- K0: pack W_ih (f32 -> bf16 [2048][416]) ----------------
__global__ void k0_pack(const float* __restrict__ wihf, const float* __restrict__ wihb,
                        u16* __restrict__ wih)
{
  int n = blockIdx.x, tid = threadIdx.x;
  const float* src = (n < 1024) ? (wihf + (size_t)n*400) : (wihb + (size_t)(n-1024)*400);
  u32* dst = (u32*)(wih + (size_t)n*416);
  if (tid < 208){
    int j = tid*2;
    u32 v = 0u;
    if (j < 400){
      float2 f = *(const float2*)(src + j);
      v = (u32)f2bf(f.x) | ((u32)f2bf(f.y) << 16);
    }
    dst[tid] = v;
  }
}

// ---------------- K0q: quantize W_hh rows to i8 MFMA fragments ----------------
__global__ __launch_bounds__(256) void k0q(
    const float* __restrict__ whhf, const float* __restrict__ whhb,
    s8* __restrict__ wq, float* __restrict__ sc2)
{
  const int row = blockIdx.x*4 + (threadIdx.x >> 6);
  const int lane = threadIdx.x & 63;
  const float* src = (row < 1024) ? (whhf + (size_t)row*256)
                                  : (whhb + (size_t)(row-1024)*256);
  f32x4 v = *(const f32x4*)(src + lane*4);
  float m = fmaxf(fmaxf(fabsf(v[0]), fabsf(v[1])), fmaxf(fabsf(v[2]), fabsf(v[3])));
  #pragma unroll
  for (int d = 1; d < 64; d <<= 1) m = fmaxf(m, __shfl_xor(m, d, 64));
  float inv = 127.f / (m + 1e-30f);
  u32 pack = 0;
  #pragma unroll
  for (int e = 0; e < 4; e++){
    int q = (int)rintf(v[e]*inv);
    q = q > 127 ? 127 : (q < -127 ? -127 : q);
    pack |= ((u32)(u8)(s8)q) << (8*e);
  }
  const int dir = row >> 10, n = row & 1023;
  const int g = n >> 8, j = n & 255, w2 = j >> 4, lr2 = j & 15;
  const int kk = lane >> 4, lq2 = (lane >> 2) & 3, e4 = lane & 3;
  u32* wq32 = (u32*)wq;
  wq32[dir*65536 + (((g*16 + w2)*4 + kk)*64 + lq2*16 + lr2)*4 + e4] = pack;
  if (lane == 0) sc2[row] = m * (1.f/16129.f);
}

// ---------------- K0b: bias sums (fp32) + wfc = fc_w @ wd (parallel) ----------------
__global__ void k0_misc(const float* bihf, const float* bhhf, const float* bihb, const float* bhhb,
                        const float* fcw, const float* wdp, float* bias, float* wfc)
{
  __shared__ float red[256];
  int tid = threadIdx.x;
  for (int n = tid; n < 2048; n += 256){
    bias[n] = (n < 1024) ? (bihf[n] + bhhf[n]) : (bihb[n-1024] + bhhb[n-1024]);
  }
  const int cur = tid & 15, part = tid >> 4;
  float s = 0.f;
  for (int k = part*32; k < part*32 + 32; k++) s += fcw[cur*512 + k] * wdp[k];
  red[tid] = s;
  __syncthreads();
  if (tid < 16){
    float t = 0.f;
    #pragma unroll
    for (int p = 0; p < 16; p++) t += red[p*16 + tid];
    wfc[tid] = t;
  }
}

// ---------------- K1: features -> feat[s*64+b][416] bf16 ----------------
__global__ __launch_bounds__(256) void k1_feat(
    const int* __restrict__ X, const int* __restrict__ tg, const int* __restrict__ ch,
    const float* __restrict__ etab, const float* __restrict__ ttab, const float* __restrict__ ctab,
    const float* __restrict__ cw, const float* __restrict__ cb, u16* __restrict__ feat)
{
  const int sb = blockIdx.x, b = blockIdx.y, tid = threadIdx.x;
  __shared__ float ce_s[66*60];
  __shared__ float w_s[150*52];
  for (int i = tid; i < 600; i += 256){
    int wl = i/150, j = i - wl*150;
    int s = sb*4 + wl;
    int idx = X[b*512 + s];
    float2 f = *(const float2*)(etab + (size_t)idx*300 + j*2);
    *(u32*)(feat + (size_t)(s*64 + b)*416 + j*2) = (u32)f2bf(f.x) | ((u32)f2bf(f.y) << 16);
  }
  for (int i = tid; i < 100; i += 256){
    int wl = i/25, j = i - wl*25;
    int s = sb*4 + wl;
    int idx = tg[b*512 + s];
    float2 f = *(const float2*)(ttab + (size_t)idx*50 + j*2);
    *(u32*)(feat + (size_t)(s*64 + b)*416 + 300 + j*2) = (u32)f2bf(f.x) | ((u32)f2bf(f.y) << 16);
  }
  if (tid < 32){
    int wl = tid>>3, j = tid&7;
    int s = sb*4 + wl;
    *(u32*)(feat + (size_t)(s*64 + b)*416 + 400 + j*2) = 0u;
  }
  for (int i = tid; i < 3300; i += 256){
    int qq = i/50, ce = i - qq*50;
    int p = sb*64 - 1 + qq;
    float v = 0.f;
    if (p >= 0 && p < 8192){
      int ci = ch[b*8192 + p];
      v = ctab[ci*50 + ce];
    }
    ce_s[qq*60 + ce] = v;
  }
  for (int i = tid; i < 7500; i += 256){
    int cc = i/150, r2 = i - cc*150;
    int ce = r2/3, dc = r2 - ce*3;
    w_s[(cc*3 + dc)*52 + ce] = cw[i];
  }
  __syncthreads();
  const int li = tid & 15, jg = tid >> 4;
  float acc[4][3];
  #pragma unroll
  for (int k=0;k<4;k++){ acc[k][0]=0.f; acc[k][1]=0.f; acc[k][2]=0.f; }
  #pragma unroll
  for (int dc = 0; dc < 3; dc++){
    for (int ceb = 0; ceb < 48; ceb += 4){
      f32x4 w0 = *(const f32x4*)&w_s[((3*jg+0)*3 + dc)*52 + ceb];
      f32x4 w1 = *(const f32x4*)&w_s[((3*jg+1)*3 + dc)*52 + ceb];
      f32x4 w2 = *(const f32x4*)&w_s[((3*jg+2)*3 + dc)*52 + ceb];
      #pragma unroll
      for (int k = 0; k < 4; k++){
        f32x4 cv = *(const f32x4*)&ce_s[(16*k + li + dc)*60 + ceb];
        #pragma unroll
        for (int e = 0; e < 4; e++){
          acc[k][0] += cv[e]*w0[e];
          acc[k][1] += cv[e]*w1[e];
          acc[k][2] += cv[e]*w2[e];
        }
      }
    }
    float w0a = w_s[((3*jg+0)*3+dc)*52 + 48], w0b = w_s[((3*jg+0)*3+dc)*52 + 49];
    float w1a = w_s[((3*jg+1)*3+dc)*52 + 48], w1b = w_s[((3*jg+1)*3+dc)*52 + 49];
    float w2a = w_s[((3*jg+2)*3+dc)*52 + 48], w2b = w_s[((3*jg+2)*3+dc)*52 + 49];
    #pragma unroll
    for (int k = 0; k < 4; k++){
      float ca = ce_s[(16*k + li + dc)*60 + 48];
      float cb2 = ce_s[(16*k + li + dc)*60 + 49];
      acc[k][0] += ca*w0a + cb2*w0b;
      acc[k][1] += ca*w1a + cb2*w1b;
      acc[k][2] += ca*w2a + cb2*w2b;
    }
  }
  #pragma unroll
  for (int m = 1; m < 16; m <<= 1)
    #pragma unroll
    for (int k=0;k<4;k++)
      #pragma unroll
      for (int c=0;c<3;c++)
        acc[k][c] = fmaxf(acc[k][c], __shfl_xor(acc[k][c], m, 64));
  if (li == 0){
    #pragma unroll
    for (int k=0;k<4;k++)
      #pragma unroll
      for (int c=0;c<3;c++){
        int cc = 3*jg + c;
        int s = sb*4 + k;
        feat[(size_t)(s*64 + b)*416 + 350 + cc] = f2bf(acc[k][c] + cb[cc]);
      }
  }
  if (tid < 128){
    int pl = tid & 63, cc = 48 + (tid >> 6);
    float a2 = 0.f;
    #pragma unroll
    for (int dc = 0; dc < 3; dc++){
      for (int ceb = 0; ceb < 48; ceb += 4){
        f32x4 wv = *(const f32x4*)&w_s[(cc*3 + dc)*52 + ceb];
        f32x4 cv = *(const f32x4*)&ce_s[(pl + dc)*60 + ceb];
        a2 += cv[0]*wv[0] + cv[1]*wv[1] + cv[2]*wv[2] + cv[3]*wv[3];
      }
      a2 += ce_s[(pl+dc)*60 + 48]*w_s[(cc*3+dc)*52 + 48]
          + ce_s[(pl+dc)*60 + 49]*w_s[(cc*3+dc)*52 + 49];
    }
    #pragma unroll
    for (int m = 1; m < 16; m <<= 1) a2 = fmaxf(a2, __shfl_xor(a2, m, 64));
    if ((tid & 15) == 0){
      int s = sb*4 + ((tid & 63) >> 4);
      feat[(size_t)(s*64 + b)*416 + 350 + cc] = f2bf(a2 + cb[cc]);
    }
  }
}

// ---------------- K2: gi = bf16(feat @ wih^T + bias)  [32768 x 2048] ----------------
__global__ __launch_bounds__(256) void k2_gemm(
    const u16* __restrict__ featp, const u16* __restrict__ wihp,
    const float* __restrict__ bias, u16* __restrict__ gi)
{
  const int m0 = blockIdx.y*128, n0 = blockIdx.x*128;
  const int tid = threadIdx.x, wv = tid>>6, lane = tid&63;
  const int lr = lane & 15, lq = lane >> 4;
  const int wm = (wv>>1)*64, wn = (wv&1)*64;
  __shared__ u16 As[4096], Bs[4096];
  f32x4 acc[4][4];
  #pragma unroll
  for (int a=0;a<4;a++)
    #pragma unroll
    for (int c=0;c<4;c++) acc[a][c] = (f32x4){0.f,0.f,0.f,0.f};
  for (int k0 = 0; k0 < 416; k0 += 32){
    __syncthreads();
    #pragma unroll
    for (int i = 0; i < 2; i++){
      int c = i*4 + wv;
      gld_lds16(featp + (size_t)(m0 + c*16 + (lane>>2))*416 + k0 + (lane&3)*8, &As[c*512]);
      gld_lds16(wihp  + (size_t)(n0 + c*16 + (lane>>2))*416 + k0 + (lane&3)*8, &Bs[c*512]);
    }
    __syncthreads();
    short8 af[4], bfr[4];
    #pragma unroll
    for (int mt=0; mt<4; mt++) af[mt]  = *(const short8*)(As + (wm + mt*16 + lr)*32 + lq*8);
    #pragma unroll
    for (int nt=0; nt<4; nt++) bfr[nt] = *(const short8*)(Bs + (wn + nt*16 + lr)*32 + lq*8);
    #pragma unroll
    for (int mt=0; mt<4; mt++)
      #pragma unroll
      for (int nt=0; nt<4; nt++)
        acc[mt][nt] = __builtin_amdgcn_mfma_f32_16x16x32_bf16(af[mt], bfr[nt], acc[mt][nt], 0,0,0);
  }
  #pragma unroll
  for (int nt=0; nt<4; nt++){
    float bv = bias[n0 + wn + nt*16 + lr];
    #pragma unroll
    for (int mt=0; mt<4; mt++)
      #pragma unroll
      for (int r=0; r<4; r++)
        gi[(size_t)(m0 + wm + mt*16 + lq*4 + r)*2048 + n0 + wn + nt*16 + lr]
            = f2bf(acc[mt][nt][r] + bv);
  }
}

// ---------------- K3: recurrent BiLSTM, 64 blocks x 512 thr, all-VGPR weights ----------------
__global__ __launch_bounds__(512, 2) void k3_lstm(
    const s8* __restrict__ wq, const float* __restrict__ sc2,
    const u16* __restrict__ gi, u16* __restrict__ hcat)
{
  const int dir = blockIdx.x >> 5;
  const int bb  = (blockIdx.x & 31) * 2;
  const int tid = threadIdx.x;
  const int w = tid >> 6, lane = tid & 63;
  const int lr = lane & 15, lq = lane >> 4;
  const int cb = tid >> 8, cj = tid & 255;

  __shared__ s8 Hs[2][4096];
  __shared__ float xbuf[2048];

  const s8* wqd = wq + dir*262144;
  int4v bq[2][4][4];
  #pragma unroll
  for (int sl = 0; sl < 2; sl++)
    #pragma unroll
    for (int g = 0; g < 4; g++)
      #pragma unroll
      for (int kk = 0; kk < 4; kk++)
        bq[sl][g][kk] = *(const int4v*)(wqd + (((((g*16 + 2*w + sl)*4 + kk)*64) + lane) << 4));

  float scl[4];
  #pragma unroll
  for (int g = 0; g < 4; g++) scl[g] = sc2[dir*1024 + g*256 + cj];

  *(uint2*)&Hs[0][tid*8] = (uint2){0u,0u};
  *(uint2*)&Hs[1][tid*8] = (uint2){0u,0u};

  float cst = 0.f;
  const ptrdiff_t dstep = dir ? -(ptrdiff_t)131072 : (ptrdiff_t)131072;
  const u16* g0 = gi + (size_t)((dir ? 511 : 0)*64 + bb + cb)*2048 + dir*1024 + cj;
  u32 gcur[4], gn1[4], gn2[4];
  #pragma unroll
  for (int g = 0; g < 4; g++) gcur[g] = g0[g*256];
  const u16* g1 = g0 + dstep;
  #pragma unroll
  for (int g = 0; g < 4; g++) gn1[g] = g1[g*256];
  const u16* gpref = g1;
  __syncthreads();

  #pragma unroll 1
  for (int t = 0; t < 512; t++){
    const int s = dir ? (511 - t) : t;
    if (t + 2 < 512) gpref += dstep;
    #pragma unroll
    for (int g = 0; g < 4; g++) gn2[g] = gpref[g*256];
    const s8* hb = Hs[t & 1];
    int4v aq[4];
    #pragma unroll
    for (int kk = 0; kk < 4; kk++)
      aq[kk] = *(const int4v*)(hb + lr*256 + ((kk*64 + lq*16) ^ (lr << 4)));
    int4v acc[2][4];
    #pragma unroll
    for (int sl = 0; sl < 2; sl++)
      #pragma unroll
      for (int g = 0; g < 4; g++) acc[sl][g] = (int4v){0,0,0,0};
    #pragma unroll
    for (int kk = 0; kk < 4; kk++)
      #pragma unroll
      for (int sl = 0; sl < 2; sl++)
        #pragma unroll
        for (int g = 0; g < 4; g++)
          acc[sl][g] = __builtin_amdgcn_mfma_i32_16x16x64_i8(aq[kk], bq[sl][g][kk], acc[sl][g], 0,0,0);
    if (lq == 0){
      #pragma unroll
      for (int sl = 0; sl < 2; sl++){
        const int j = (2*w + sl)*16 + lr;
        #pragma unroll
        for (int r = 0; r < 2; r++){
          f32x4 v = (f32x4){(float)acc[sl][0][r], (float)acc[sl][1][r],
                            (float)acc[sl][2][r], (float)acc[sl][3][r]};
          *(f32x4*)&xbuf[(r*256 + j)*4] = v;
        }
      }
    }
    bar_l();
    f32x4 p = *(const f32x4*)&xbuf[tid*4];
    float g4[4];
    #pragma unroll
    for (int g = 0; g < 4; g++) g4[g] = bf2f((u16)gcur[g]) + p[g]*scl[g];
    float iv = sigf(g4[0]), fv = sigf(g4[1]);
    float gg = tanh_f(g4[2]), ov = sigf(g4[3]);
    float c = fv*cst + iv*gg;
    cst = c;
    float h = ov * tanh_f(c);
    hcat[(size_t)(s*64 + bb + cb)*512 + dir*256 + cj] = f2bf(h);
    int q = (int)rintf(h * 127.f);
    Hs[(t + 1) & 1][cb*256 + (cj ^ (cb << 4))] = (s8)q;
    #pragma unroll
    for (int g = 0; g < 4; g++){ gcur[g] = gn1[g]; gn1[g] = gn2[g]; }
    bar_l();
  }
}

// ---------------- K4: P = Hcat @ fc_w^T + fc_b + lm*wfc  [32768 x 16] fp32 ----------------
__global__ __launch_bounds__(256) void k4_fc(
    const u16* __restrict__ hcat, const float* __restrict__ fcw, const float* __restrict__ fcb,
    const float* __restrict__ lmp, const float* __restrict__ wfc, float* __restrict__ Pout)
{
  const int wv = threadIdx.x >> 6, lane = threadIdx.x & 63;
  const int lr = lane & 15, lq = lane >> 4;
  const int mt = blockIdx.x*4 + wv;
  short8 bfr[16];
  #pragma unroll
  for (int kk = 0; kk < 16; kk++){
    const float* wr = fcw + (size_t)lr*512 + kk*32 + lq*8;
    f32x4 w0 = *(const f32x4*)wr;
    f32x4 w1 = *(const f32x4*)(wr + 4);
    short8 sv;
    #pragma unroll
    for (int e = 0; e < 4; e++){ sv[e] = (short)f2bf(w0[e]); sv[4+e] = (short)f2bf(w1[e]); }
    bfr[kk] = sv;
  }
  f32x4 acc = (f32x4){0.f,0.f,0.f,0.f};
  #pragma unroll
  for (int kk = 0; kk < 16; kk++){
    short8 af = *(const short8*)(hcat + (size_t)(mt*16 + lr)*512 + kk*32 + lq*8);
    acc = __builtin_amdgcn_mfma_f32_16x16x32_bf16(af, bfr[kk], acc, 0,0,0);
  }
  const int cur = lr;
  float fb = fcb[cur];
  float wf = wfc[cur];
  #pragma unroll
  for (int r = 0; r < 4; r++){
    int m = mt*16 + lq*4 + r;
    int b = m & 63, s = m >> 6;
    float lmv = lmp[b*512 + s];
    Pout[(size_t)m*16 + cur] = acc[r] + fb + lmv*wf;
  }
}

// ---------------- K5: Viterbi — de-scratched (static regs, 4x unroll) ----------------
__global__ __launch_bounds__(64) void k5_vit(
    const float* __restrict__ Pg, const float* __restrict__ Am,
    float* __restrict__ dout, float* __restrict__ dl, u8* __restrict__ psi)
{
  const int b = blockIdx.x, lane = threadIdx.x;
  const int cur = lane >> 2, q = lane & 3;
  float Ar[4];
  #pragma unroll
  for (int r = 0; r < 4; r++) Ar[r] = Am[(4*q + r)*16 + cur];
  float val = Pg[(size_t)b*16 + cur];
  if (q == 0) dl[(size_t)b*16 + cur] = val;

#define FSTEP(X, S) { \
    float best = -3.0e38f; int bi = 0; \
    _Pragma("unroll") \
    for (int r = 0; r < 4; r++){ \
      float dp = __shfl(val, (4*q + r)*4, 64); \
      float sc = (dp + Ar[r]) + (X); \
      if (sc > best){ best = sc; bi = 4*q + r; } \
    } \
    { float ov = __shfl_xor(best, 1, 64); int oi = __shfl_xor(bi, 1, 64); \
      if (ov > best || (ov == best && oi < bi)){ best = ov; bi = oi; } } \
    { float ov = __shfl_xor(best, 2, 64); int oi = __shfl_xor(bi, 2, 64); \
      if (ov > best || (ov == best && oi < bi)){ best = ov; bi = oi; } } \
    val = best; \
    if (q == 0){ \
      dl[(size_t)((S)*64 + b)*16 + cur] = best; \
      psi[(size_t)((S)*64 + b)*16 + cur] = (u8)bi; \
    } }

  // forward scan, 4x unroll, named prefetch regs (rule #20: no runtime-indexed arrays)
  float x0 = Pg[(size_t)(1*64 + b)*16 + cur];
  float x1 = Pg[(size_t)(2*64 + b)*16 + cur];
  float x2 = Pg[(size_t)(3*64 + b)*16 + cur];
  float x3 = Pg[(size_t)(4*64 + b)*16 + cur];
  for (int s = 1; s < 512; s += 4){
    FSTEP(x0, s);
    if (s + 4 < 512) x0 = Pg[(size_t)((s+4)*64 + b)*16 + cur];
    if (s + 1 < 512) FSTEP(x1, s+1);
    if (s + 5 < 512) x1 = Pg[(size_t)((s+5)*64 + b)*16 + cur];
    if (s + 2 < 512) FSTEP(x2, s+2);
    if (s + 6 < 512) x2 = Pg[(size_t)((s+6)*64 + b)*16 + cur];
    if (s + 3 < 512) FSTEP(x3, s+3);
    if (s + 7 < 512) x3 = Pg[(size_t)((s+7)*64 + b)*16 + cur];
  }
#undef FSTEP

  // argmax over final deltas (first-index tie-break)
  float bv = val; int bix = cur;
  #pragma unroll
  for (int m = 1; m < 64; m <<= 1){
    float ov = __shfl_xor(bv, m, 64);
    int   oi = __shfl_xor(bix, m, 64);
    if (ov > bv || (ov == bv && oi < bix)){ bv = ov; bix = oi; }
  }
  int tag = bix;
  float score = bv;
  if (lane == 0) dout[b*512 + 511] = (float)tag;

#define BSTEP(PV, DV, T) { \
    int prev = __shfl((PV), tag, 64); \
    score += __shfl((DV), prev, 64); \
    if (lane == 0) dout[b*512 + (T)] = (float)prev; \
    tag = prev; }

  // backtrace: iteration t uses psi[t+1], dl[t]; 4x unroll, named regs
  int   p0 = 0, p1 = 0, p2 = 0, p3 = 0;
  float d0 = 0.f, d1 = 0.f, d2 = 0.f, d3 = 0.f;
  if (lane < 16){
    p0 = psi[(size_t)(511*64 + b)*16 + lane]; d0 = dl[(size_t)(510*64 + b)*16 + lane];
    p1 = psi[(size_t)(510*64 + b)*16 + lane]; d1 = dl[(size_t)(509*64 + b)*16 + lane];
    p2 = psi[(size_t)(509*64 + b)*16 + lane]; d2 = dl[(size_t)(508*64 + b)*16 + lane];
    p3 = psi[(size_t)(508*64 + b)*16 + lane]; d3 = dl[(size_t)(507*64 + b)*16 + lane];
  }
  for (int t = 510; t >= 0; t -= 4){
    BSTEP(p0, d0, t);
    if (t - 4 >= 0 && lane < 16){
      p0 = psi[(size_t)((t-3)*64 + b)*16 + lane]; d0 = dl[(size_t)((t-4)*64 + b)*16 + lane];
    }
    if (t - 1 >= 0) BSTEP(p1, d1, t-1);
    if (t - 5 >= 0 && lane < 16){
      p1 = psi[(size_t)((t-4)*64 + b)*16 + lane]; d1 = dl[(size_t)((t-5)*64 + b)*16 + lane];
    }
    if (t - 2 >= 0) BSTEP(p2, d2, t-2);
    if (t - 6 >= 0 && lane < 16){
      p2 = psi[(size_t)((t-5)*64 + b)*16 + lane]; d2 = dl[(size_t)((t-6)*64 + b)*16 + lane];
    }
    if (t - 3 >= 0) BSTEP(p3, d3, t-3);
    if (t - 7 >= 0 && lane < 16){
      p3 = psi[(size_t)((t-6)*64 + b)*16 + lane]; d3 = dl[(size_t)((t-7)*64 + b)*16 + lane];
    }
  }
#undef BSTEP
  if (lane == 0) dout[32768 + b] = score;
}

// ---------------- launcher ----------------
extern "C" void kernel_launch(void* const* d_in, const int* in_sizes, int n_in,
                              void* d_out, int out_size, void* d_ws, size_t ws_size,
                              hipStream_t stream)
{
  (void)in_sizes; (void)n_in; (void)out_size;
  if (ws_size < REQUIRED) return;

  const int*   X    = (const int*)d_in[0];
  const float* lm   = (const float*)d_in[1];
  const int*   tg   = (const int*)d_in[2];
  const int*   ch   = (const int*)d_in[3];
  const float* etab = (const float*)d_in[4];
  const float* ttab = (const float*)d_in[5];
  const float* ctab = (const float*)d_in[6];
  const float* cw   = (const float*)d_in[7];
  const float* cb   = (const float*)d_in[8];
  const float* wihf = (const float*)d_in[9];
  const float* whhf = (const float*)d_in[10];
  const float* bihf = (const float*)d_in[11];
  const float* bhhf = (const float*)d_in[12];
  const float* wihb = (const float*)d_in[13];
  const float* whhb = (const float*)d_in[14];
  const float* bihb = (const float*)d_in[15];
  const float* bhhb = (const float*)d_in[16];
  const float* fcw  = (const float*)d_in[17];
  const float* fcb  = (const float*)d_in[18];
  const float* Am   = (const float*)d_in[19];
  const float* wdp  = (const float*)d_in[20];

  char* ws = (char*)d_ws;
  u16*   gi   = (u16*)(ws + OFF_GI);
  u16*   feat = (u16*)(ws + OFF_B);
  u16*   hcat = (u16*)(ws + OFF_B);
  u16*   wih  = (u16*)(ws + OFF_WIH);
  s8*    wq   = (s8*)(ws + OFF_WQ);
  float* sc2  = (float*)(ws + OFF_SC);
  float* Pg   = (float*)(ws + OFF_P);
  float* dlt  = (float*)(ws + OFF_DL);
  u8*    psi  = (u8*)(ws + OFF_PSI);
  float* bias = (float*)(ws + OFF_BIAS);
  float* wfc  = (float*)(ws + OFF_WFC);
  float* dout = (float*)d_out;

  k0_pack<<<2048, 256, 0, stream>>>(wihf, wihb, wih);
  k0q<<<512, 256, 0, stream>>>(whhf, whhb, wq, sc2);
  k0_misc<<<1, 256, 0, stream>>>(bihf, bhhf, bihb, bhhb, fcw, wdp, bias, wfc);
  k1_feat<<<dim3(128, 64), 256, 0, stream>>>(X, tg, ch, etab, ttab, ctab, cw, cb, feat);
  k2_gemm<<<dim3(16, 256), 256, 0, stream>>>(feat, wih, bias, gi);
  k3_lstm<<<64, 512, 0, stream>>>(wq, sc2, gi, hcat);
  k4_fc<<<512, 256, 0, stream>>>(hcat, fcw, fcb, lm, wfc, Pg);
  k5_vit<<<64, 64, 0, stream>>>(Pg, Am, dout, dlt, psi);
}